// Round 16
// baseline (379.909 us; speedup 1.0000x reference)
//
#include <hip/hip_runtime.h>
#include <math.h>

// ---- problem constants ----
#define TT 2048
#define HH 1024
#define NHEADS 16
#define NKVH 4
#define HDIM 64
#define NEXP 32
#define TOPK_ 4
#define NGRP 4
#define IMID 384
#define ISHARED 384
#define QKV_W (24*64)   // 1536
#define EPS_ 1e-5f
#define MAXSB 288       // max slot-blocks: 8192/32 + 32 (= 8*36)
#define NSPLITS 80      // attn split-entries per head

typedef __attribute__((ext_vector_type(8))) short short8;
typedef __attribute__((ext_vector_type(4))) float f32x4;

__device__ __forceinline__ ushort f2bf(float x) {
  union { float f; unsigned u; } v; v.f = x;
  unsigned r = v.u + 0x7fffu + ((v.u >> 16) & 1u);
  return (ushort)(r >> 16);
}
__device__ __forceinline__ float bf2f(ushort u) {
  union { unsigned i; float f; } v; v.i = (unsigned)u << 16; return v.f;
}

// async global->LDS, 16B per lane; lds dst = wave-uniform base + lane*16
__device__ __forceinline__ void gload16(const void* g, void* l) {
  __builtin_amdgcn_global_load_lds(
      (const __attribute__((address_space(1))) unsigned int*)g,
      (__attribute__((address_space(3))) unsigned int*)l, 16, 0, 0);
}

// =====================================================================
// MFMA fragment layouts (16x16x32 bf16), verified rounds 1-15:
//   A-frag lane l: A[row=l&15][k in {4g+j, 16+4g+j}], g=l>>4
//   B-frag lane l: B[k in {4g+j, 16+4g+j}][col=l&15]
//   C lane l: C[row=(l>>4)*4+i][col=l&15]
// Packed tile (global): 4096 B = 4 planes x 1024 B; B-frag for (plane
// lg, col c) = 16 contiguous bytes at lg*1024 + ((c*16)^(((c>>3)&7)<<4)).
// Permuted activation row (bf16): A-frag (row, k-tile t, group lg) = 16
// contiguous bytes at row*LD + t*32 + lg*8 (ushorts).
// r15 lesson: reg-direct loops are latency-bound at ~1 iter of prefetch
// depth; the lever is WAVE COUNT (occupancy), not load expression.
// =====================================================================
__device__ __forceinline__ short8 read_a_frag64(const ushort* As, int lg, int row) {
  return *(const short8*)(As + ((lg * 64 + (row ^ lg)) * 8));
}
__device__ __forceinline__ short8 read_b_frag(const ushort* Bs, int lg, int col) {
  int boff = (col * 16) ^ (((col >> 3) & 7) << 4);
  return *(const short8*)((const char*)Bs + lg * 1024 + boff);
}

// B-tile staging from f32 (pack kernels only)
__device__ __forceinline__ void stage_B_tile(const float* __restrict__ B, int ldb,
                                             int k0, int col0, ushort* Bs, int tid) {
  int a = tid >> 4;
  int cG = tid & 15;
  int k = 2 * a;
  const float* p0 = B + (size_t)(k0 + k) * ldb + col0 + cG * 4;
  const float* p1 = p0 + ldb;
  float4 r0 = *(const float4*)p0;
  float4 r1 = *(const float4*)p1;
  int gg = (k & 15) >> 2;
  int slot = (k & 3) + ((k >> 4) << 2);
  float v0[4] = {r0.x, r0.y, r0.z, r0.w};
  float v1[4] = {r1.x, r1.y, r1.z, r1.w};
  char* plane = (char*)Bs + gg * 1024;
  #pragma unroll
  for (int j = 0; j < 4; ++j) {
    int c = cG * 4 + j;
    unsigned pk = (unsigned)f2bf(v0[j]) | ((unsigned)f2bf(v1[j]) << 16);
    int boff = ((c * 16) ^ (((c >> 3) & 7) << 4)) + slot * 2;
    *(unsigned*)(plane + boff) = pk;
  }
}

// ---------------------------------------------------------------------
// Pack kernel v2: 4 k-tiles per block (launch-overhead amortized).
// dst tile (kt, nt) at (kt*gridDim.x + nt)*2048 ushorts.
// ---------------------------------------------------------------------
__global__ __launch_bounds__(256) void pack_B4_kernel(
    const float* __restrict__ src, ushort* __restrict__ dst, int N) {
  __shared__ ushort tileB[2048];
  int tid = threadIdx.x;
  int ntn = gridDim.x;
  #pragma unroll
  for (int kk = 0; kk < 4; ++kk) {
    int kt = blockIdx.y * 4 + kk;
    stage_B_tile(src, N, kt * 32, blockIdx.x * 64, tileB, tid);
    __syncthreads();
    size_t toff = ((size_t)kt * ntn + blockIdx.x) * 2048;
    *(short8*)(dst + toff + tid * 8) = *(const short8*)(tileB + tid * 8);
    __syncthreads();
  }
}

// ---------------------------------------------------------------------
// Dense GEMM (r10 verified): BM=64, BN=64, ring-4, dist-3.
// ---------------------------------------------------------------------
__global__ __launch_bounds__(256) void gemm64_bb(
    const ushort* __restrict__ Ab, const ushort* __restrict__ Bpk,
    float* __restrict__ C, int M, int N, int K) {
  __shared__ ushort As[4][2048];
  __shared__ ushort Bs[4][2048];
  int tid = threadIdx.x;
  int row0 = blockIdx.y * 64, col0 = blockIdx.x * 64;
  int ntn = N >> 6;
  int wid = tid >> 6, lane = tid & 63;
  int lg = lane >> 4, lr = lane & 15;
  int wrow = (wid >> 1) * 32, wcol = (wid & 1) * 32;
  const ushort* asrc = Ab + (size_t)(row0 + (lane ^ wid)) * K + wid * 8;
  const ushort* bsrc = Bpk + (size_t)blockIdx.x * 2048 + wid * 512 + lane * 8;
  const int NT = K >> 5;
  f32x4 acc[2][2] = {};

  auto issue = [&](int tt) {
    int b = tt & 3;
    gload16(asrc + tt * 32, &As[b][wid * 512]);
    gload16(bsrc + (size_t)tt * ntn * 2048, &Bs[b][wid * 512]);
  };
  issue(0); issue(1); issue(2);
  for (int t = 0; t < NT; ++t) {
    int ahead = NT - 1 - t;
    if (ahead >= 2)      asm volatile("s_waitcnt vmcnt(4)" ::: "memory");
    else if (ahead == 1) asm volatile("s_waitcnt vmcnt(2)" ::: "memory");
    else                 asm volatile("s_waitcnt vmcnt(0)" ::: "memory");
    __builtin_amdgcn_s_barrier();
    if (t + 3 < NT) issue(t + 3);
    int cb = t & 3;
    short8 af0 = read_a_frag64(&As[cb][0], lg, wrow + lr);
    short8 af1 = read_a_frag64(&As[cb][0], lg, wrow + 16 + lr);
    #pragma unroll
    for (int nn = 0; nn < 2; ++nn) {
      short8 bf_ = read_b_frag(&Bs[cb][0], lg, wcol + nn * 16 + lr);
      acc[0][nn] = __builtin_amdgcn_mfma_f32_16x16x32_bf16(af0, bf_, acc[0][nn], 0, 0, 0);
      acc[1][nn] = __builtin_amdgcn_mfma_f32_16x16x32_bf16(af1, bf_, acc[1][nn], 0, 0, 0);
    }
  }
  #pragma unroll
  for (int mm = 0; mm < 2; ++mm)
    #pragma unroll
    for (int nn = 0; nn < 2; ++nn) {
      int row = row0 + wrow + mm * 16 + lg * 4;
      int col = col0 + wcol + nn * 16 + lr;
      #pragma unroll
      for (int i = 0; i < 4; ++i)
        C[(size_t)(row + i) * N + col] = acc[mm][nn][i];
    }
}

// ---------------------------------------------------------------------
// MoE up-proj v6: REGISTER-DIRECT, 16-row wave tiles -> 2x wave count.
// grid (MAXSB, 6); wave -> (rowhalf = wid>>1, colhalf = wid&1), bz = by.
// Per iter: 5 unconditional loads (peeled tail) + 4 MFMAs.
// ---------------------------------------------------------------------
__global__ __launch_bounds__(256) void moe_up_pk(
    const ushort* __restrict__ hln2b, const ushort* __restrict__ Wpk,
    const int* __restrict__ perm, const int* __restrict__ offs,
    const int* __restrict__ counts, const int* __restrict__ sb_e,
    const int* __restrict__ sb_base, const int* __restrict__ nsb,
    ushort* __restrict__ actb) {
  int b = blockIdx.x;
  int sb = ((b & 7) * 36) + (b >> 3);   // XCD-chunked remap
  if (sb >= *nsb) return;
  int e = sb_e[sb];
  int base = sb_base[sb];
  int start = offs[e];
  int nt = min(32, counts[e] - base);
  int tid = threadIdx.x;
  int wid = tid >> 6, lane = tid & 63;
  int lg = lane >> 4, lr = lane & 15;
  int bz = blockIdx.y;                  // 0..5
  int rh = wid >> 1;                    // rowhalf
  int wcol = (wid & 1) * 32;            // colhalf
  int row = rh * 16 + lr;
  int rowc = min(row, nt - 1);          // clamp; masked at write
  int tok = perm[start + base + rowc] >> 2;
  const ushort* ap = hln2b + (size_t)tok * HH + lg * 8;
  int c0 = wcol + lr, c1 = wcol + 16 + lr;
  int sw0 = (c0 * 16) ^ (((c0 >> 3) & 7) << 4);
  int sw1 = (c1 * 16) ^ (((c1 >> 3) & 7) << 4);
  const char* gbase = (const char*)Wpk + ((size_t)(e * 32) * 12 + bz) * 4096 + lg * 1024;
  const char* ubase = gbase + (size_t)6 * 4096;
  const size_t bstep = (size_t)12 * 4096;
  f32x4 ag0 = {}, ag1 = {}, au0 = {}, au1 = {};
  short8 ac  = *(const short8*)ap;
  short8 g0c = *(const short8*)(gbase + sw0);
  short8 g1c = *(const short8*)(gbase + sw1);
  short8 u0c = *(const short8*)(ubase + sw0);
  short8 u1c = *(const short8*)(ubase + sw1);
  #pragma unroll 4
  for (int t = 0; t < 31; ++t) {
    const char* gb = gbase + (size_t)(t + 1) * bstep;
    const char* ub = ubase + (size_t)(t + 1) * bstep;
    short8 an  = *(const short8*)(ap + (t + 1) * 32);
    short8 g0n = *(const short8*)(gb + sw0);
    short8 g1n = *(const short8*)(gb + sw1);
    short8 u0n = *(const short8*)(ub + sw0);
    short8 u1n = *(const short8*)(ub + sw1);
    ag0 = __builtin_amdgcn_mfma_f32_16x16x32_bf16(ac, g0c, ag0, 0, 0, 0);
    ag1 = __builtin_amdgcn_mfma_f32_16x16x32_bf16(ac, g1c, ag1, 0, 0, 0);
    au0 = __builtin_amdgcn_mfma_f32_16x16x32_bf16(ac, u0c, au0, 0, 0, 0);
    au1 = __builtin_amdgcn_mfma_f32_16x16x32_bf16(ac, u1c, au1, 0, 0, 0);
    ac = an; g0c = g0n; g1c = g1n; u0c = u0n; u1c = u1n;
  }
  ag0 = __builtin_amdgcn_mfma_f32_16x16x32_bf16(ac, g0c, ag0, 0, 0, 0);
  ag1 = __builtin_amdgcn_mfma_f32_16x16x32_bf16(ac, g1c, ag1, 0, 0, 0);
  au0 = __builtin_amdgcn_mfma_f32_16x16x32_bf16(ac, u0c, au0, 0, 0, 0);
  au1 = __builtin_amdgcn_mfma_f32_16x16x32_bf16(ac, u1c, au1, 0, 0, 0);
  // epilogue: SiLU*mul -> permuted bf16
  f32x4 ag[2] = {ag0, ag1}, au[2] = {au0, au1};
  #pragma unroll
  for (int nn = 0; nn < 2; ++nn) {
    int pcol = bz * 64 + wcol + ((lr >> 2) << 3) + (nn << 2) + (lr & 3);
    #pragma unroll
    for (int i = 0; i < 4; ++i) {
      int rr = rh * 16 + lg * 4 + i;
      if (rr < nt) {
        float gv = ag[nn][i], uv = au[nn][i];
        float av = gv / (1.f + expf(-gv)) * uv;
        actb[(size_t)(start + base + rr) * IMID + pcol] = f2bf(av);
      }
    }
  }
}

// ---------------------------------------------------------------------
// MoE down-proj v5 (r15 verified): REGISTER-DIRECT, peeled final iter.
// grid (MAXSB, 8); wave -> (nct = by*2 + (wid>>1), colhalf = wid&1).
// ---------------------------------------------------------------------
__global__ __launch_bounds__(256) void moe_down_pk(
    const ushort* __restrict__ actb, const ushort* __restrict__ Wpk,
    const int* __restrict__ offs, const int* __restrict__ counts,
    const int* __restrict__ sb_e, const int* __restrict__ sb_base,
    const int* __restrict__ nsb, ushort* __restrict__ partialb) {
  int b = blockIdx.x;
  int sb = ((b & 7) * 36) + (b >> 3);
  if (sb >= *nsb) return;
  int e = sb_e[sb];
  int base = sb_base[sb];
  int start = offs[e];
  int nt = min(32, counts[e] - base);
  int tid = threadIdx.x;
  int wid = tid >> 6, lane = tid & 63;
  int lg = lane >> 4, lr = lane & 15;
  int nct = blockIdx.y * 2 + (wid >> 1);   // 0..15
  int wcol = (wid & 1) * 32;
  const ushort* a0p = actb + (size_t)(start + base + min(lr, nt - 1)) * IMID + lg * 8;
  const ushort* a1p = actb + (size_t)(start + base + min(16 + lr, nt - 1)) * IMID + lg * 8;
  int c0 = wcol + lr, c1 = wcol + 16 + lr;
  int sw0 = (c0 * 16) ^ (((c0 >> 3) & 7) << 4);
  int sw1 = (c1 * 16) ^ (((c1 >> 3) & 7) << 4);
  const char* bbase = (const char*)Wpk + ((size_t)(e * 12) * 16 + nct) * 4096 + lg * 1024;
  const size_t bstep = (size_t)16 * 4096;
  f32x4 acc[2][2] = {};
  short8 a0c = *(const short8*)(a0p);
  short8 a1c = *(const short8*)(a1p);
  short8 b0c = *(const short8*)(bbase + sw0);
  short8 b1c = *(const short8*)(bbase + sw1);
  #pragma unroll 4
  for (int t = 0; t < 11; ++t) {
    const char* bb = bbase + (size_t)(t + 1) * bstep;
    short8 a0n = *(const short8*)(a0p + (t + 1) * 32);
    short8 a1n = *(const short8*)(a1p + (t + 1) * 32);
    short8 b0n = *(const short8*)(bb + sw0);
    short8 b1n = *(const short8*)(bb + sw1);
    acc[0][0] = __builtin_amdgcn_mfma_f32_16x16x32_bf16(a0c, b0c, acc[0][0], 0, 0, 0);
    acc[0][1] = __builtin_amdgcn_mfma_f32_16x16x32_bf16(a0c, b1c, acc[0][1], 0, 0, 0);
    acc[1][0] = __builtin_amdgcn_mfma_f32_16x16x32_bf16(a1c, b0c, acc[1][0], 0, 0, 0);
    acc[1][1] = __builtin_amdgcn_mfma_f32_16x16x32_bf16(a1c, b1c, acc[1][1], 0, 0, 0);
    a0c = a0n; a1c = a1n; b0c = b0n; b1c = b1n;
  }
  acc[0][0] = __builtin_amdgcn_mfma_f32_16x16x32_bf16(a0c, b0c, acc[0][0], 0, 0, 0);
  acc[0][1] = __builtin_amdgcn_mfma_f32_16x16x32_bf16(a0c, b1c, acc[0][1], 0, 0, 0);
  acc[1][0] = __builtin_amdgcn_mfma_f32_16x16x32_bf16(a1c, b0c, acc[1][0], 0, 0, 0);
  acc[1][1] = __builtin_amdgcn_mfma_f32_16x16x32_bf16(a1c, b1c, acc[1][1], 0, 0, 0);
  #pragma unroll
  for (int mm = 0; mm < 2; ++mm)
    #pragma unroll
    for (int nn = 0; nn < 2; ++nn)
      #pragma unroll
      for (int i = 0; i < 4; ++i) {
        int rr = mm * 16 + lg * 4 + i;
        if (rr < nt)
          partialb[(size_t)(start + base + rr) * HH + nct * 64 + wcol + nn * 16 + lr] = f2bf(acc[mm][nn][i]);
      }
}

// =====================================================================
// residual add + RMSNorm; emits f32 sum, f32 ln, permuted bf16 ln.
// =====================================================================
__global__ __launch_bounds__(256) void add_rms_kernel(
    const float* __restrict__ a, const float* __restrict__ b,
    const float* __restrict__ w, float* __restrict__ sum_out,
    float* __restrict__ ln_out, ushort* __restrict__ lnb) {
  int t = blockIdx.x, tid = threadIdx.x;
  float4 x = reinterpret_cast<const float4*>(a + (size_t)t*HH)[tid];
  float4 y = reinterpret_cast<const float4*>(b + (size_t)t*HH)[tid];
  x.x += y.x; x.y += y.y; x.z += y.z; x.w += y.w;
  float ss = x.x*x.x + x.y*x.y + x.z*x.z + x.w*x.w;
  #pragma unroll
  for (int off = 1; off < 64; off <<= 1) ss += __shfl_xor(ss, off);
  __shared__ float wsum[4];
  int wid = tid >> 6, lane = tid & 63;
  if (lane == 0) wsum[wid] = ss;
  __syncthreads();
  float tot = wsum[0] + wsum[1] + wsum[2] + wsum[3];
  float r = rsqrtf(tot * (1.0f/HH) + EPS_);
  reinterpret_cast<float4*>(sum_out + (size_t)t*HH)[tid] = x;
  float4 wl = reinterpret_cast<const float4*>(w)[tid];
  float4 o = make_float4(x.x*r*wl.x, x.y*r*wl.y, x.z*r*wl.z, x.w*r*wl.w);
  reinterpret_cast<float4*>(ln_out + (size_t)t*HH)[tid] = o;
  ushort4 ub;
  ub.x = f2bf(o.x); ub.y = f2bf(o.y); ub.z = f2bf(o.z); ub.w = f2bf(o.w);
  int dst = ((tid >> 3) << 5) + ((tid & 3) << 3) + (((tid >> 2) & 1) << 2);
  *(ushort4*)(lnb + (size_t)t * HH + dst) = ub;
}

// =====================================================================
// per-(t,head) QK RMSNorm + RoPE, in-place (f32)
// =====================================================================
__global__ __launch_bounds__(256) void qk_norm_rope_kernel(
    float* __restrict__ qkv, const float* __restrict__ qw,
    const float* __restrict__ kw, const int* __restrict__ pos) {
  int t = blockIdx.x;
  int hh = blockIdx.y * 4 + (threadIdx.x >> 6);
  int lane = threadIdx.x & 63;
  float* p = qkv + (size_t)t * QKV_W + hh * HDIM;
  float x = p[lane];
  float ss = x * x;
  #pragma unroll
  for (int off = 1; off < 64; off <<= 1) ss += __shfl_xor(ss, off);
  float r = rsqrtf(ss * (1.0f/HDIM) + EPS_);
  float wv = (hh < NHEADS ? qw : kw)[lane];
  float xn = x * r * wv;
  float partner = __shfl_xor(xn, 16);
  float out = xn;
  if (lane < 32) {
    int i = lane & 15;
    float inv = powf(10000.0f, -(float)i / 16.0f);
    float ang = (float)pos[t] * inv;
    float cv = cosf(ang), sv = sinf(ang);
    out = (lane < 16) ? (xn * cv - partner * sv) : (partner * sv + xn * cv);
  }
  p[lane] = out;
}

// =====================================================================
// pack_KV: rope'd K -> A-tile images; V -> B-tile images. grid (T/32, NKVH)
// =====================================================================
__global__ __launch_bounds__(256) void pack_KV_kernel(
    const float* __restrict__ qkv, ushort* __restrict__ Kpk,
    ushort* __restrict__ Vpk) {
  __shared__ ushort kimg[2048];
  __shared__ ushort vimg[2048];
  int tid = threadIdx.x;
  int kt = blockIdx.x, kvh = blockIdx.y;
  {
    int c = tid >> 7, t2 = tid & 127;
    int g = t2 & 3, r = t2 >> 2;
    const float* kp = qkv + (size_t)(kt*32 + r) * QKV_W + NHEADS*HDIM + kvh*HDIM + 32*c + 4*g;
    float4 h0 = *(const float4*)kp;
    float4 h1 = *(const float4*)(kp + 16);
    short8 v;
    v[0]=(short)f2bf(h0.x); v[1]=(short)f2bf(h0.y); v[2]=(short)f2bf(h0.z); v[3]=(short)f2bf(h0.w);
    v[4]=(short)f2bf(h1.x); v[5]=(short)f2bf(h1.y); v[6]=(short)f2bf(h1.z); v[7]=(short)f2bf(h1.w);
    *(short8*)(kimg + c*1024 + (g*32 + (r^g))*8) = v;
  }
  stage_B_tile(qkv + (size_t)(NHEADS+NKVH)*HDIM + (size_t)kvh*HDIM, QKV_W, kt*32, 0, vimg, tid);
  __syncthreads();
  size_t toff = ((size_t)(kvh * (TT/32) + kt)) * 2048;
  *(short8*)(Kpk + toff + tid * 8) = *(const short8*)(kimg + tid * 8);
  *(short8*)(Vpk + toff + tid * 8) = *(const short8*)(vimg + tid * 8);
}

// =====================================================================
// Attention v3 (r12 verified): split-KV + fixed-max log2 softmax.
// =====================================================================
__global__ __launch_bounds__(256) void attn_v3_kernel(
    const float* __restrict__ qkv, const ushort* __restrict__ Kpk,
    const ushort* __restrict__ Vpk, ushort* __restrict__ ob,
    float* __restrict__ po, float* __restrict__ pl) {
  __shared__ ushort Ks[3][2048];
  __shared__ ushort Vs[3][2048];
  int tid = threadIdx.x;
  int wid = tid >> 6, lane = tid & 63;
  int lg = lane >> 4, lr = lane & 15;
  int h = blockIdx.y;
  int f = blockIdx.x;
  int g = 0;
  while (f >= 4 * (g + 1) * (g + 2)) ++g;
  int r_ = f - 4 * g * (g + 1);
  int ns = g + 1;
  int qb = 8 * g + r_ / ns;
  int s = r_ % ns;
  int tiles_total = 2 * qb + 2;
  int per = (tiles_total + ns - 1) / ns;
  int lo = s * per;
  int nloc = min(per, tiles_total - lo);
  int kvh = h >> 2;
  int q0 = qb * 64 + wid * 16;
  int qg = q0 + lr;
  const float SCL = 0.125f * 1.44269504f;
  const float FM = 16.0f;

  const float* qrow = qkv + (size_t)qg * QKV_W + h * HDIM;
  short8 qfr[2];
  #pragma unroll
  for (int c = 0; c < 2; ++c) {
    float4 a = *(const float4*)(qrow + 32*c + 4*lg);
    float4 b = *(const float4*)(qrow + 32*c + 4*lg + 16);
    short8 v;
    v[0]=(short)f2bf(a.x*SCL); v[1]=(short)f2bf(a.y*SCL); v[2]=(short)f2bf(a.z*SCL); v[3]=(short)f2bf(a.w*SCL);
    v[4]=(short)f2bf(b.x*SCL); v[5]=(short)f2bf(b.y*SCL); v[6]=(short)f2bf(b.z*SCL); v[7]=(short)f2bf(b.w*SCL);
    qfr[c] = v;
  }

  const ushort* ksrc = Kpk + (size_t)(kvh * (TT/32) + lo) * 2048 + wid * 512 + lane * 8;
  const ushort* vsrc = Vpk + (size_t)(kvh * (TT/32) + lo) * 2048 + wid * 512 + lane * 8;

  f32x4 o_acc[4] = {};
  float l_st = 0.f;

  auto issue = [&](int tt) {
    int b = tt % 3;
    gload16(ksrc + (size_t)tt * 2048, &Ks[b][wid * 512]);
    gload16(vsrc + (size_t)tt * 2048, &Vs[b][wid * 512]);
  };
  issue(0);
  if (nloc > 1) issue(1);
  for (int tt = 0; tt < nloc; ++tt) {
    if (tt < nloc - 1) asm volatile("s_waitcnt vmcnt(2)" ::: "memory");
    else               asm volatile("s_waitcnt vmcnt(0)" ::: "memory");
    __builtin_amdgcn_s_barrier();
    if (tt + 2 < nloc) issue(tt + 2);
    int t = lo + tt;
    if (t * 32 > q0 + 15) continue;
    int cb = tt % 3;
    f32x4 st[2];
    #pragma unroll
    for (int n = 0; n < 2; ++n) {
      short8 kf0 = *(const short8*)(&Ks[cb][(lg*32 + ((16*n + lr) ^ lg)) * 8]);
      short8 kf1 = *(const short8*)(&Ks[cb][1024 + (lg*32 + ((16*n + lr) ^ lg)) * 8]);
      f32x4 z = {};
      z = __builtin_amdgcn_mfma_f32_16x16x32_bf16(kf0, qfr[0], z, 0, 0, 0);
      st[n] = __builtin_amdgcn_mfma_f32_16x16x32_bf16(kf1, qfr[1], z, 0, 0, 0);
    }
    float p[2][4];
    float psum = 0.f;
    if (t * 32 + 31 <= q0) {
      #pragma unroll
      for (int n = 0; n < 2; ++n)
        #pragma unroll
        for (int i = 0; i < 4; ++i) {
          float pv = exp2f(st[n][i] - FM);
          p[n][i] = pv; psum += pv;
        }
    } else {
      #pragma unroll
      for (int n = 0; n < 2; ++n)
        #pragma unroll
        for (int i = 0; i < 4; ++i) {
          int kvg = t*32 + 16*n + 4*lg + i;
          float pv = (kvg <= qg) ? exp2f(st[n][i] - FM) : 0.f;
          p[n][i] = pv; psum += pv;
        }
    }
    psum += __shfl_xor(psum, 16);
    psum += __shfl_xor(psum, 32);
    l_st += psum;
    union { unsigned u[4]; short8 s8; } pu;
    asm volatile("v_cvt_pk_bf16_f32 %0, %1, %2" : "=v"(pu.u[0]) : "v"(p[0][0]), "v"(p[0][1]));
    asm volatile("v_cvt_pk_bf16_f32 %0, %1, %2" : "=v"(pu.u[1]) : "v"(p[0][2]), "v"(p[0][3]));
    asm volatile("v_cvt_pk_bf16_f32 %0, %1, %2" : "=v"(pu.u[2]) : "v"(p[1][0]), "v"(p[1][1]));
    asm volatile("v_cvt_pk_bf16_f32 %0, %1, %2" : "=v"(pu.u[3]) : "v"(p[1][2]), "v"(p[1][3]));
    short8 pa = pu.s8;
    #pragma unroll
    for (int nd = 0; nd < 4; ++nd) {
      short8 vf = read_b_frag(&Vs[cb][0], lg, 16*nd + lr);
      o_acc[nd] = __builtin_amdgcn_mfma_f32_16x16x32_bf16(pa, vf, o_acc[nd], 0, 0, 0);
    }
  }

  if (ns == 1) {
    #pragma unroll
    for (int i = 0; i < 4; ++i) {
      float lrow = __shfl(l_st, 4*lg + i);
      float inv = 1.0f / lrow;
      int row = q0 + 4*lg + i;
      ushort* op = ob + (size_t)row * (NHEADS*HDIM) + h * HDIM;
      #pragma unroll
      for (int nd = 0; nd < 4; ++nd) {
        int pcol = ((nd >> 1) << 5) + ((lr >> 2) << 3) + ((nd & 1) << 2) + (lr & 3);
        op[pcol] = f2bf(o_acc[nd][i] * inv);
      }
    }
  } else {
    float* pob = po + ((size_t)f * NHEADS + h) * 4096;
    #pragma unroll
    for (int nd = 0; nd < 4; ++nd)
      #pragma unroll
      for (int i = 0; i < 4; ++i)
        pob[(wid * 16 + lg * 4 + i) * 64 + 16 * nd + lr] = o_acc[nd][i];
    if (lg == 0)
      pl[((size_t)f * NHEADS + h) * 64 + wid * 16 + lr] = l_st;
  }
}

// =====================================================================
// attn combine (r12 verified)
// =====================================================================
__global__ __launch_bounds__(256) void attn_combine_kernel(
    const float* __restrict__ po, const float* __restrict__ pl,
    ushort* __restrict__ ob) {
  int h = blockIdx.x;
  int qb = 8 + blockIdx.y;
  int g = qb >> 3;
  int ns = g + 1;
  int f0 = 4 * g * (g + 1) + (qb - 8 * g) * ns;
  int tid = threadIdx.x;
  int r = tid >> 2, c = tid & 3;
  float acc[16] = {};
  float lsum = 0.f;
  for (int s = 0; s < ns; ++s) {
    size_t base = ((size_t)(f0 + s) * NHEADS + h) * 4096 + r * 64 + c * 16;
    #pragma unroll
    for (int j = 0; j < 4; ++j) {
      float4 v = *(const float4*)(po + base + j * 4);
      acc[j*4+0] += v.x; acc[j*4+1] += v.y; acc[j*4+2] += v.z; acc[j*4+3] += v.w;
    }
    lsum += pl[((size_t)(f0 + s) * NHEADS + h) * 64 + r];
  }
  float inv = 1.0f / lsum;
  int row = qb * 64 + r;
  ushort* op = ob + (size_t)row * (NHEADS*HDIM) + h * HDIM + (c >> 1) * 32 + (c & 1) * 4;
  #pragma unroll
  for (int a = 0; a < 4; ++a) {
    ushort4 u;
    u.x = f2bf(acc[a*4+0] * inv); u.y = f2bf(acc[a*4+1] * inv);
    u.z = f2bf(acc[a*4+2] * inv); u.w = f2bf(acc[a*4+3] * inv);
    *(ushort4*)(op + a * 8) = u;
  }
}

// =====================================================================
// router: wave-parallel (r8 verified)
// =====================================================================
__global__ __launch_bounds__(256) void router_kernel(
    const float* __restrict__ hln, const float* __restrict__ Wg,
    const float* __restrict__ bias, int* __restrict__ sel_e,
    float* __restrict__ sel_w) {
  __shared__ float hid[4][HH];
  int tid = threadIdx.x, wid = tid >> 6, lane = tid & 63;
  int t = blockIdx.x * 4 + wid;
  const float4* src = (const float4*)(hln + (size_t)t * HH);
  float4* dst = (float4*)hid[wid];
  #pragma unroll
  for (int j = 0; j < 4; ++j) dst[j * 64 + lane] = src[j * 64 + lane];
  int e = lane & 31, half = lane >> 5;
  const float* wp = Wg + (size_t)(half * 512) * NEXP + e;
  const float* hp = hid[wid] + half * 512;
  float p = 0.f;
  #pragma unroll 8
  for (int h = 0; h < 512; ++h) p += hp[h] * wp[(size_t)h * NEXP];
  p += __shfl_xor(p, 32);
  float sc = 1.0f / (1.0f + expf(-p));
  float sfc = sc + bias[e];
  float m1 = sfc, m2 = -1e30f;
  #pragma unroll
  for (int off = 1; off <= 4; off <<= 1) {
    float om1 = __shfl_xor(m1, off), om2 = __shfl_xor(m2, off);
    float hi_ = fmaxf(m1, om1);
    float lo_ = fmaxf(fminf(m1, om1), fmaxf(m2, om2));
    m1 = hi_; m2 = lo_;
  }
  float gs = m1 + m2;
  float gv[4] = {__shfl(gs, 0), __shfl(gs, 8), __shfl(gs, 16), __shfl(gs, 24)};
  int g1 = 0; float b1 = gv[0];
  #pragma unroll
  for (int g = 1; g < 4; ++g) if (gv[g] > b1) { b1 = gv[g]; g1 = g; }
  int g2 = -1; float b2 = -1e30f;
  #pragma unroll
  for (int g = 0; g < 4; ++g) if (g != g1 && gv[g] > b2) { b2 = gv[g]; g2 = g; }
  bool keep = ((e >> 3) == g1) || ((e >> 3) == g2);
  float cand = keep ? sfc : -1e30f;
  int ids[4]; float wv[4]; float wsum = 0.f;
  #pragma unroll
  for (int s = 0; s < 4; ++s) {
    float v = cand; int ix = e;
    #pragma unroll
    for (int off = 1; off < 64; off <<= 1) {
      float ov = __shfl_xor(v, off); int oix = __shfl_xor(ix, off);
      if (ov > v || (ov == v && oix < ix)) { v = ov; ix = oix; }
    }
    ids[s] = ix;
    if (e == ix) cand = -1e30f;
    float w = __shfl(sc, ix);
    wv[s] = w; wsum += w;
  }
  if (lane == 0) {
    #pragma unroll
    for (int s = 0; s < 4; ++s) {
      sel_e[t * 4 + s] = ids[s];
      sel_w[t * 4 + s] = wv[s] / wsum;
    }
  }
}

__global__ __launch_bounds__(256) void count_kernel(
    const int* __restrict__ sel_e, int* __restrict__ counts) {
  int e = blockIdx.x, tid = threadIdx.x;
  int c = 0;
  for (int i = tid; i < TT * TOPK_; i += 256) c += (sel_e[i] == e);
  #pragma unroll
  for (int off = 1; off < 64; off <<= 1) c += __shfl_xor(c, off);
  __shared__ int wsum[4];
  if ((tid & 63) == 0) wsum[tid >> 6] = c;
  __syncthreads();
  if (tid == 0) counts[e] = wsum[0] + wsum[1] + wsum[2] + wsum[3];
}

// scan + flat slot-block table (BM=32 granularity)
__global__ void scan_kernel(const int* __restrict__ counts,
                            int* __restrict__ offs, int* __restrict__ cursor,
                            int* __restrict__ sb_e, int* __restrict__ sb_base,
                            int* __restrict__ nsb) {
  if (threadIdx.x == 0) {
    int acc = 0, n = 0;
    for (int e = 0; e < NEXP; ++e) {
      offs[e] = acc; cursor[e] = acc;
      int c = counts[e];
      for (int b = 0; b < c; b += 32) { sb_e[n] = e; sb_base[n] = b; ++n; }
      acc += c;
    }
    *nsb = n;
  }
}

__global__ void scatter_kernel(const int* __restrict__ sel_e,
                               int* __restrict__ cursor, int* __restrict__ perm,
                               int* __restrict__ ipos) {
  int i = blockIdx.x * 256 + threadIdx.x;
  if (i < TT * TOPK_) {
    int e = sel_e[i];
    int pos = atomicAdd(&cursor[e], 1);
    perm[pos] = i;
    ipos[i] = pos;
  }
}

// =====================================================================
// shared-expert SiLU*mul -> permuted bf16 (4 cols/thread)
// =====================================================================
__global__ __launch_bounds__(256) void silu_shared_kernel(
    const float* __restrict__ gus, ushort* __restrict__ shsb) {
  int i = blockIdx.x * 256 + threadIdx.x;
  if (i < TT * (ISHARED/4)) {
    int t = i / (ISHARED/4), k = i % (ISHARED/4);
    const float* gp = gus + (size_t)t * (2*ISHARED) + k * 4;
    float4 g4 = *(const float4*)gp;
    float4 u4 = *(const float4*)(gp + ISHARED);
    ushort4 r;
    r.x = f2bf(g4.x / (1.f + expf(-g4.x)) * u4.x);
    r.y = f2bf(g4.y / (1.f + expf(-g4.y)) * u4.y);
    r.z = f2bf(g4.z / (1.f + expf(-g4.z)) * u4.z);
    r.w = f2bf(g4.w / (1.f + expf(-g4.w)) * u4.w);
    int pdst = ((k >> 3) << 5) + ((k & 3) << 3) + (((k >> 2) & 1) << 2);
    *(ushort4*)(shsb + (size_t)t * ISHARED + pdst) = r;
  }
}

// =====================================================================
// final combine (bf16 partial)
// =====================================================================
__global__ __launch_bounds__(256) void final_combine_kernel(
    const ushort* __restrict__ partialb, const float* __restrict__ sel_w,
    const int* __restrict__ ipos, const float* __restrict__ shared_out,
    float* __restrict__ out_hidden) {
  int t = blockIdx.x, tid = threadIdx.x;
  float w0 = sel_w[t*4], w1 = sel_w[t*4+1], w2 = sel_w[t*4+2], w3 = sel_w[t*4+3];
  int p0 = ipos[t*4], p1 = ipos[t*4+1], p2 = ipos[t*4+2], p3 = ipos[t*4+3];
  ushort4 a0 = *(const ushort4*)(partialb + (size_t)p0*HH + tid*4);
  ushort4 a1 = *(const ushort4*)(partialb + (size_t)p1*HH + tid*4);
  ushort4 a2 = *(const ushort4*)(partialb + (size_t)p2*HH + tid*4);
  ushort4 a3 = *(const ushort4*)(partialb + (size_t)p3*HH + tid*4);
  float4 sh = reinterpret_cast<const float4*>(shared_out + (size_t)t*HH)[tid];
  float4 r;
  r.x = (w0*bf2f(a0.x) + w1*bf2f(a1.x) + w2*bf2f(a2.x) + w3*bf2f(a3.x)) + sh.x;
  r.y = (w0*bf2f(a0.y) + w1*bf2f(a1.y) + w2*bf2f(a2.y) + w3*bf2f(a3.y)) + sh.y;
  r.z = (w0*bf2f(a0.z) + w1*bf2f(a1.z) + w2*bf2f(a2.z) + w3*bf2f(a3.z)) + sh.z;
  r.w = (w0*bf2f(a0.w) + w1*bf2f(a1.w) + w2*bf2f(a2.w) + w3*bf2f(a3.w)) + sh.w;
  reinterpret_cast<float4*>(out_hidden + (size_t)t*HH)[tid] = r;
}

// =====================================================================
extern "C" void kernel_launch(void* const* d_in, const int* in_sizes, int n_in,
                              void* d_out, int out_size, void* d_ws, size_t ws_size,
                              hipStream_t stream) {
  const float* hidden   = (const float*)d_in[0];
  const float* residual = (const float*)d_in[1];
  const float* in_ln_w  = (const float*)d_in[2];
  const float* post_ln_w= (const float*)d_in[3];
  const float* q_norm_w = (const float*)d_in[4];
  const float* k_norm_w = (const float*)d_in[5];
  const float* Wqkv     = (const float*)d_in[6];
  const float* Wo       = (const float*)d_in[7];
  const float* Wg       = (const float*)d_in[8];
  const float* gate_bias= (const float*)d_in[9];
  const float* Wgu      = (const float*)d_in[10];
  const float* Wd       = (const float*)d_in[11];
  const float* Wgu_sh   = (const float*)d_in[12];
  const float* Wd_sh    = (const float*)d_in[13];
  const int*   positions= (const int*)d_in[14];
  float* out = (float*)d_out;

  float* f = (float*)d_ws;
  size_t off = 0;
  float* R_A   = f + off; off += (size_t)TT*HH;
  float* HLN   = f + off; off += (size_t)TT*HH;
  float* QKV   = f + off; off += (size_t)TT*QKV_W;        // reused as gus
  float* OATT  = f + off; off += (size_t)TT*HH;           // DSH output (shared_out)
  float* HLN2  = f + off; off += (size_t)TT*HH;
  float* SELW  = f + off; off += (size_t)TT*TOPK_;
  float* PO    = f + off; off += (size_t)NSPLITS*NHEADS*4096;  // attn partial O
  float* PL    = f + off; off += (size_t)NSPLITS*NHEADS*64;    // attn partial l
  ushort* HLNB  = (ushort*)(f + off); off += (size_t)TT*HH/2;
  ushort* HLN2B = (ushort*)(f + off); off += (size_t)TT*HH/2;
  ushort* OATTB = (ushort*)(f + off); off += (size_t)TT*HH/2;
  ushort* SHSB  = (ushort*)(f + off); off += (size_t)TT*ISHARED/2;
  ushort* KPK   = (ushort*)(f + off); off += (size_t)NKVH*(TT/32)*2048/2;
  ushort* VPK   = (ushort*)(f + off); off += (size_t)NKVH*(TT/32)*2048/2;
  ushort* ACTB  = (ushort*)(f + off); off += (size_t)(TT*TOPK_ + 128)*IMID/2;
  ushort* PARTB = (ushort*)(f + off); off += (size_t)TT*TOPK_*HH/2;
  ushort* PK_QKV = (ushort*)(f + off); off += (size_t)HH*QKV_W/2;
  ushort* PK_WO  = (ushort*)(f + off); off += (size_t)HH*HH/2;
  ushort* PK_WGU = (ushort*)(f + off); off += (size_t)NEXP*HH*(2*IMID)/2;
  ushort* PK_WD  = (ushort*)(f + off); off += (size_t)NEXP*IMID*HH/2;
  ushort* PK_GUSH= (ushort*)(f + off); off += (size_t)HH*(2*ISHARED)/2;
  ushort* PK_DSH = (ushort*)(f + off); off += (size_t)ISHARED*HH/2;
  int* ibase   = (int*)(f + off);
  int* SELE    = ibase;
  int* PERM    = ibase + TT*TOPK_;
  int* IPOS    = ibase + 2*TT*TOPK_;
  int* COUNTS  = ibase + 3*TT*TOPK_;
  int* OFFS    = COUNTS + NEXP;
  int* CURSOR  = OFFS + NEXP;
  int* SB_E    = CURSOR + NEXP;
  int* SB_BASE = SB_E + MAXSB;
  int* NSB     = SB_BASE + MAXSB;

  // 0. pack all weights to bf16 tile images (4 k-tiles per block)
  pack_B4_kernel<<<dim3(QKV_W/64, HH/32/4), 256, 0, stream>>>(Wqkv, PK_QKV, QKV_W);
  pack_B4_kernel<<<dim3(HH/64, HH/32/4), 256, 0, stream>>>(Wo, PK_WO, HH);
  pack_B4_kernel<<<dim3((2*IMID)/64, NEXP*HH/32/4), 256, 0, stream>>>(Wgu, PK_WGU, 2*IMID);
  pack_B4_kernel<<<dim3(HH/64, NEXP*IMID/32/4), 256, 0, stream>>>(Wd, PK_WD, HH);
  pack_B4_kernel<<<dim3((2*ISHARED)/64, HH/32/4), 256, 0, stream>>>(Wgu_sh, PK_GUSH, 2*ISHARED);
  pack_B4_kernel<<<dim3(HH/64, ISHARED/32/4), 256, 0, stream>>>(Wd_sh, PK_DSH, HH);

  // 1. pipeline
  add_rms_kernel<<<TT, 256, 0, stream>>>(hidden, residual, in_ln_w, R_A, HLN, HLNB);
  gemm64_bb<<<dim3(QKV_W/64, TT/64), 256, 0, stream>>>(HLNB, PK_QKV, QKV, TT, QKV_W, HH);
  qk_norm_rope_kernel<<<dim3(TT, 5), 256, 0, stream>>>(QKV, q_norm_w, k_norm_w, positions);
  pack_KV_kernel<<<dim3(TT/32, NKVH), 256, 0, stream>>>(QKV, KPK, VPK);
  attn_v3_kernel<<<dim3(NSPLITS, NHEADS), 256, 0, stream>>>(QKV, KPK, VPK, OATTB, PO, PL);
  attn_combine_kernel<<<dim3(NHEADS, 24), 256, 0, stream>>>(PO, PL, OATTB);
  gemm64_bb<<<dim3(HH/64, TT/64), 256, 0, stream>>>(OATTB, PK_WO, HLN, TT, HH, HH);
  add_rms_kernel<<<TT, 256, 0, stream>>>(HLN, R_A, post_ln_w, out + (size_t)TT*HH, HLN2, HLN2B);
  router_kernel<<<TT/4, 256, 0, stream>>>(HLN2, Wg, gate_bias, SELE, SELW);
  count_kernel<<<NEXP, 256, 0, stream>>>(SELE, COUNTS);
  scan_kernel<<<1, 64, 0, stream>>>(COUNTS, OFFS, CURSOR, SB_E, SB_BASE, NSB);
  scatter_kernel<<<(TT*TOPK_ + 255)/256, 256, 0, stream>>>(SELE, CURSOR, PERM, IPOS);
  moe_up_pk<<<dim3(MAXSB, 6), 256, 0, stream>>>(HLN2B, PK_WGU, PERM, OFFS, COUNTS, SB_E, SB_BASE, NSB, ACTB);
  moe_down_pk<<<dim3(MAXSB, 8), 256, 0, stream>>>(ACTB, PK_WD, OFFS, COUNTS, SB_E, SB_BASE, NSB, PARTB);
  gemm64_bb<<<dim3((2*ISHARED)/64, TT/64), 256, 0, stream>>>(HLN2B, PK_GUSH, QKV, TT, 2*ISHARED, HH);
  silu_shared_kernel<<<(TT*(ISHARED/4) + 255)/256, 256, 0, stream>>>(QKV, SHSB);
  gemm64_bb<<<dim3(HH/64, TT/64), 256, 0, stream>>>(SHSB, PK_DSH, OATT, TT, HH, ISHARED);
  final_combine_kernel<<<TT, 256, 0, stream>>>(PARTB, SELW, IPOS, OATT, out);
}

// Round 17
// 341.868 us; speedup vs baseline: 1.1113x; 1.1113x over previous
//
#include <hip/hip_runtime.h>
#include <math.h>

// ---- problem constants ----
#define TT 2048
#define HH 1024
#define NHEADS 16
#define NKVH 4
#define HDIM 64
#define NEXP 32
#define TOPK_ 4
#define NGRP 4
#define IMID 384
#define ISHARED 384
#define QKV_W (24*64)   // 1536
#define EPS_ 1e-5f
#define MAXSB 288       // max slot-blocks: 8192/32 + 32 (= 8*36)
#define NSPLITS 80      // attn split-entries per head

typedef __attribute__((ext_vector_type(8))) short short8;
typedef __attribute__((ext_vector_type(4))) float f32x4;

__device__ __forceinline__ ushort f2bf(float x) {
  union { float f; unsigned u; } v; v.f = x;
  unsigned r = v.u + 0x7fffu + ((v.u >> 16) & 1u);
  return (ushort)(r >> 16);
}
__device__ __forceinline__ float bf2f(ushort u) {
  union { unsigned i; float f; } v; v.i = (unsigned)u << 16; return v.f;
}

// async global->LDS, 16B per lane; lds dst = wave-uniform base + lane*16
__device__ __forceinline__ void gload16(const void* g, void* l) {
  __builtin_amdgcn_global_load_lds(
      (const __attribute__((address_space(1))) unsigned int*)g,
      (__attribute__((address_space(3))) unsigned int*)l, 16, 0, 0);
}

// =====================================================================
// MFMA fragment layouts (16x16x32 bf16), verified rounds 1-16:
//   A-frag lane l: A[row=l&15][k in {4g+j, 16+4g+j}], g=l>>4
//   B-frag lane l: B[k in {4g+j, 16+4g+j}][col=l&15]
//   C lane l: C[row=(l>>4)*4+i][col=l&15]
// A LDS plane (32-row): [g][32][8], row^g swizzle, plane g at g*256.
// A LDS plane (64-row): [g][64][8], row^g swizzle.
// B LDS plane: 4 planes x 1024B, 16B-granular column XOR swizzle.
// Packed tile (global): 4096 B; B-frag for (plane lg, col c) = 16
// contiguous bytes at lg*1024 + ((c*16)^(((c>>3)&7)<<4)).
// Permuted activation row (bf16): A-frag (row, k-tile t, group lg) = 16
// contiguous bytes at row*LD + t*32 + lg*8 (ushorts).
// Ledger: best build = r13 (LDS ring MoE). Verified win: moe_up v5
// reg-direct peeled (60us vs 66). moe_down reg-direct = regression.
// =====================================================================
__device__ __forceinline__ short8 read_a_frag32(const ushort* As, int lg, int row) {
  return *(const short8*)(As + ((lg * 32 + (row ^ lg)) * 8));
}
__device__ __forceinline__ short8 read_a_frag64(const ushort* As, int lg, int row) {
  return *(const short8*)(As + ((lg * 64 + (row ^ lg)) * 8));
}
__device__ __forceinline__ short8 read_b_frag(const ushort* Bs, int lg, int col) {
  int boff = (col * 16) ^ (((col >> 3) & 7) << 4);
  return *(const short8*)((const char*)Bs + lg * 1024 + boff);
}

// B-tile staging from f32 (pack kernels only)
__device__ __forceinline__ void stage_B_tile(const float* __restrict__ B, int ldb,
                                             int k0, int col0, ushort* Bs, int tid) {
  int a = tid >> 4;
  int cG = tid & 15;
  int k = 2 * a;
  const float* p0 = B + (size_t)(k0 + k) * ldb + col0 + cG * 4;
  const float* p1 = p0 + ldb;
  float4 r0 = *(const float4*)p0;
  float4 r1 = *(const float4*)p1;
  int gg = (k & 15) >> 2;
  int slot = (k & 3) + ((k >> 4) << 2);
  float v0[4] = {r0.x, r0.y, r0.z, r0.w};
  float v1[4] = {r1.x, r1.y, r1.z, r1.w};
  char* plane = (char*)Bs + gg * 1024;
  #pragma unroll
  for (int j = 0; j < 4; ++j) {
    int c = cG * 4 + j;
    unsigned pk = (unsigned)f2bf(v0[j]) | ((unsigned)f2bf(v1[j]) << 16);
    int boff = ((c * 16) ^ (((c >> 3) & 7) << 4)) + slot * 2;
    *(unsigned*)(plane + boff) = pk;
  }
}

// ---------------------------------------------------------------------
// Pack kernel: f32 KxN matrix -> bf16 pre-swizzled B-tile images.
// ---------------------------------------------------------------------
__global__ __launch_bounds__(256) void pack_B_kernel(
    const float* __restrict__ src, ushort* __restrict__ dst, int N) {
  __shared__ ushort tileB[2048];
  int tid = threadIdx.x;
  stage_B_tile(src, N, blockIdx.y * 32, blockIdx.x * 64, tileB, tid);
  __syncthreads();
  size_t toff = ((size_t)blockIdx.y * gridDim.x + blockIdx.x) * 2048;
  *(short8*)(dst + toff + tid * 8) = *(const short8*)(tileB + tid * 8);
}

// ---------------------------------------------------------------------
// Dense GEMM (r10 verified): BM=64, BN=64, ring-4, dist-3.
// ---------------------------------------------------------------------
__global__ __launch_bounds__(256) void gemm64_bb(
    const ushort* __restrict__ Ab, const ushort* __restrict__ Bpk,
    float* __restrict__ C, int M, int N, int K) {
  __shared__ ushort As[4][2048];
  __shared__ ushort Bs[4][2048];
  int tid = threadIdx.x;
  int row0 = blockIdx.y * 64, col0 = blockIdx.x * 64;
  int ntn = N >> 6;
  int wid = tid >> 6, lane = tid & 63;
  int lg = lane >> 4, lr = lane & 15;
  int wrow = (wid >> 1) * 32, wcol = (wid & 1) * 32;
  const ushort* asrc = Ab + (size_t)(row0 + (lane ^ wid)) * K + wid * 8;
  const ushort* bsrc = Bpk + (size_t)blockIdx.x * 2048 + wid * 512 + lane * 8;
  const int NT = K >> 5;
  f32x4 acc[2][2] = {};

  auto issue = [&](int tt) {
    int b = tt & 3;
    gload16(asrc + tt * 32, &As[b][wid * 512]);
    gload16(bsrc + (size_t)tt * ntn * 2048, &Bs[b][wid * 512]);
  };
  issue(0); issue(1); issue(2);
  for (int t = 0; t < NT; ++t) {
    int ahead = NT - 1 - t;
    if (ahead >= 2)      asm volatile("s_waitcnt vmcnt(4)" ::: "memory");
    else if (ahead == 1) asm volatile("s_waitcnt vmcnt(2)" ::: "memory");
    else                 asm volatile("s_waitcnt vmcnt(0)" ::: "memory");
    __builtin_amdgcn_s_barrier();
    if (t + 3 < NT) issue(t + 3);
    int cb = t & 3;
    short8 af0 = read_a_frag64(&As[cb][0], lg, wrow + lr);
    short8 af1 = read_a_frag64(&As[cb][0], lg, wrow + 16 + lr);
    #pragma unroll
    for (int nn = 0; nn < 2; ++nn) {
      short8 bf_ = read_b_frag(&Bs[cb][0], lg, wcol + nn * 16 + lr);
      acc[0][nn] = __builtin_amdgcn_mfma_f32_16x16x32_bf16(af0, bf_, acc[0][nn], 0, 0, 0);
      acc[1][nn] = __builtin_amdgcn_mfma_f32_16x16x32_bf16(af1, bf_, acc[1][nn], 0, 0, 0);
    }
  }
  #pragma unroll
  for (int mm = 0; mm < 2; ++mm)
    #pragma unroll
    for (int nn = 0; nn < 2; ++nn) {
      int row = row0 + wrow + mm * 16 + lg * 4;
      int col = col0 + wcol + nn * 16 + lr;
      #pragma unroll
      for (int i = 0; i < 4; ++i)
        C[(size_t)(row + i) * N + col] = acc[mm][nn][i];
    }
}

// ---------------------------------------------------------------------
// MoE up-proj v5 (r15-verified 60us): REGISTER-DIRECT, peeled final
// iteration (all in-loop prefetch loads unconditional -> counted vmcnt).
// 4 waves: wave -> (bz = by*2 + (wid>>1), colhalf = wid&1), 32x32 tile.
// grid (MAXSB, 3). XCD-chunked sb remap keeps weight slices L2-local.
// ---------------------------------------------------------------------
__global__ __launch_bounds__(256) void moe_up_pk(
    const ushort* __restrict__ hln2b, const ushort* __restrict__ Wpk,
    const int* __restrict__ perm, const int* __restrict__ offs,
    const int* __restrict__ counts, const int* __restrict__ sb_e,
    const int* __restrict__ sb_base, const int* __restrict__ nsb,
    ushort* __restrict__ actb) {
  int b = blockIdx.x;
  int sb = ((b & 7) * 36) + (b >> 3);
  if (sb >= *nsb) return;
  int e = sb_e[sb];
  int base = sb_base[sb];
  int start = offs[e];
  int nt = min(32, counts[e] - base);
  int tid = threadIdx.x;
  int wid = tid >> 6, lane = tid & 63;
  int lg = lane >> 4, lr = lane & 15;
  int bz = blockIdx.y * 2 + (wid >> 1);   // 0..5
  int wcol = (wid & 1) * 32;
  int tok0 = perm[start + base + min(lr, nt - 1)] >> 2;
  int tok1 = perm[start + base + min(16 + lr, nt - 1)] >> 2;
  const ushort* a0p = hln2b + (size_t)tok0 * HH + lg * 8;
  const ushort* a1p = hln2b + (size_t)tok1 * HH + lg * 8;
  int c0 = wcol + lr, c1 = wcol + 16 + lr;
  int sw0 = (c0 * 16) ^ (((c0 >> 3) & 7) << 4);
  int sw1 = (c1 * 16) ^ (((c1 >> 3) & 7) << 4);
  const char* gbase = (const char*)Wpk + ((size_t)(e * 32) * 12 + bz) * 4096 + lg * 1024;
  const char* ubase = gbase + (size_t)6 * 4096;
  const size_t bstep = (size_t)12 * 4096;
  f32x4 accg[2][2] = {}, accu[2][2] = {};
  short8 a0c = *(const short8*)(a0p);
  short8 a1c = *(const short8*)(a1p);
  short8 g0c = *(const short8*)(gbase + sw0);
  short8 g1c = *(const short8*)(gbase + sw1);
  short8 u0c = *(const short8*)(ubase + sw0);
  short8 u1c = *(const short8*)(ubase + sw1);
  #pragma unroll 4
  for (int t = 0; t < 31; ++t) {
    const char* gb = gbase + (size_t)(t + 1) * bstep;
    const char* ub = ubase + (size_t)(t + 1) * bstep;
    short8 a0n = *(const short8*)(a0p + (t + 1) * 32);
    short8 a1n = *(const short8*)(a1p + (t + 1) * 32);
    short8 g0n = *(const short8*)(gb + sw0);
    short8 g1n = *(const short8*)(gb + sw1);
    short8 u0n = *(const short8*)(ub + sw0);
    short8 u1n = *(const short8*)(ub + sw1);
    accg[0][0] = __builtin_amdgcn_mfma_f32_16x16x32_bf16(a0c, g0c, accg[0][0], 0, 0, 0);
    accg[0][1] = __builtin_amdgcn_mfma_f32_16x16x32_bf16(a0c, g1c, accg[0][1], 0, 0, 0);
    accg[1][0] = __builtin_amdgcn_mfma_f32_16x16x32_bf16(a1c, g0c, accg[1][0], 0, 0, 0);
    accg[1][1] = __builtin_amdgcn_mfma_f32_16x16x32_bf16(a1c, g1c, accg[1][1], 0, 0, 0);
    accu[0][0] = __builtin_amdgcn_mfma_f32_16x16x32_bf16(a0c, u0c, accu[0][0], 0, 0, 0);
    accu[0][1] = __builtin_amdgcn_mfma_f32_16x16x32_bf16(a0c, u1c, accu[0][1], 0, 0, 0);
    accu[1][0] = __builtin_amdgcn_mfma_f32_16x16x32_bf16(a1c, u0c, accu[1][0], 0, 0, 0);
    accu[1][1] = __builtin_amdgcn_mfma_f32_16x16x32_bf16(a1c, u1c, accu[1][1], 0, 0, 0);
    a0c = a0n; a1c = a1n; g0c = g0n; g1c = g1n; u0c = u0n; u1c = u1n;
  }
  accg[0][0] = __builtin_amdgcn_mfma_f32_16x16x32_bf16(a0c, g0c, accg[0][0], 0, 0, 0);
  accg[0][1] = __builtin_amdgcn_mfma_f32_16x16x32_bf16(a0c, g1c, accg[0][1], 0, 0, 0);
  accg[1][0] = __builtin_amdgcn_mfma_f32_16x16x32_bf16(a1c, g0c, accg[1][0], 0, 0, 0);
  accg[1][1] = __builtin_amdgcn_mfma_f32_16x16x32_bf16(a1c, g1c, accg[1][1], 0, 0, 0);
  accu[0][0] = __builtin_amdgcn_mfma_f32_16x16x32_bf16(a0c, u0c, accu[0][0], 0, 0, 0);
  accu[0][1] = __builtin_amdgcn_mfma_f32_16x16x32_bf16(a0c, u1c, accu[0][1], 0, 0, 0);
  accu[1][0] = __builtin_amdgcn_mfma_f32_16x16x32_bf16(a1c, u0c, accu[1][0], 0, 0, 0);
  accu[1][1] = __builtin_amdgcn_mfma_f32_16x16x32_bf16(a1c, u1c, accu[1][1], 0, 0, 0);
  // epilogue: SiLU*mul -> permuted bf16
  #pragma unroll
  for (int mm = 0; mm < 2; ++mm)
    #pragma unroll
    for (int nn = 0; nn < 2; ++nn) {
      int pcol = bz * 64 + wcol + ((lr >> 2) << 3) + (nn << 2) + (lr & 3);
      #pragma unroll
      for (int i = 0; i < 4; ++i) {
        int rr = mm * 16 + lg * 4 + i;
        if (rr < nt) {
          float gv = accg[mm][nn][i], uv = accu[mm][nn][i];
          float av = gv / (1.f + expf(-gv)) * uv;
          actb[(size_t)(start + base + rr) * IMID + pcol] = f2bf(av);
        }
      }
    }
}

// ---------------------------------------------------------------------
// MoE down-proj v3 (r13-verified best): LDS ring-3, flat slot-block
// table, XCD-chunked swizzle. grid (MAXSB, HH/64).
// ---------------------------------------------------------------------
__global__ __launch_bounds__(256) void moe_down_pk(
    const ushort* __restrict__ actb, const ushort* __restrict__ Wpk,
    const int* __restrict__ offs, const int* __restrict__ counts,
    const int* __restrict__ sb_e, const int* __restrict__ sb_base,
    const int* __restrict__ nsb, ushort* __restrict__ partialb) {
  int b = blockIdx.x;
  int sb = ((b & 7) * 36) + (b >> 3);   // XCD-chunked remap
  if (sb >= *nsb) return;
  int e = sb_e[sb];
  int base = sb_base[sb];
  int start = offs[e];
  int nt = min(32, counts[e] - base);
  __shared__ ushort As[3][1024];
  __shared__ ushort Bs[3][2048];
  int tid = threadIdx.x;
  int bz = blockIdx.y, col0 = bz * 64;
  int wid = tid >> 6, lane = tid & 63;
  int lg = lane >> 4, lr = lane & 15;
  int wrow = (wid >> 1) * 16, wcol = (wid & 1) * 32;
  const ushort* bt0 = Wpk + ((size_t)(e * 12) * 16 + bz) * 2048 + wid * 512 + lane * 8;
  int ga = wid * 2 + (lane >> 5);
  const ushort* asrcA = actb + (size_t)(start + base + ((lane & 31) ^ ga)) * IMID + ga * 8;
  const int NT = IMID >> 5;   // 12
  f32x4 acc[2] = {};

  auto issue = [&](int tt) {
    int bb = tt % 3;
    if (wid < 2) gload16(asrcA + tt * 32, &As[bb][wid * 512]);
    gload16(bt0 + (size_t)tt * 16 * 2048, &Bs[bb][wid * 512]);
  };
  issue(0); issue(1);
  for (int t = 0; t < NT; ++t) {
    if (t < NT - 1) {
      if (wid < 2) asm volatile("s_waitcnt vmcnt(2)" ::: "memory");
      else         asm volatile("s_waitcnt vmcnt(1)" ::: "memory");
    } else {
      asm volatile("s_waitcnt vmcnt(0)" ::: "memory");
    }
    __builtin_amdgcn_s_barrier();
    if (t + 2 < NT) issue(t + 2);
    int cb = t % 3;
    short8 af = read_a_frag32(&As[cb][0], lg, wrow + lr);
    #pragma unroll
    for (int nn = 0; nn < 2; ++nn) {
      short8 bf_ = read_b_frag(&Bs[cb][0], lg, wcol + nn * 16 + lr);
      acc[nn] = __builtin_amdgcn_mfma_f32_16x16x32_bf16(af, bf_, acc[nn], 0, 0, 0);
    }
  }
  #pragma unroll
  for (int nn = 0; nn < 2; ++nn)
    #pragma unroll
    for (int i = 0; i < 4; ++i) {
      int rr = wrow + lg * 4 + i;
      if (rr < nt)
        partialb[(size_t)(start + base + rr) * HH + col0 + wcol + nn * 16 + lr] = f2bf(acc[nn][i]);
    }
}

// =====================================================================
// residual add + RMSNorm; emits f32 sum, f32 ln, permuted bf16 ln.
// =====================================================================
__global__ __launch_bounds__(256) void add_rms_kernel(
    const float* __restrict__ a, const float* __restrict__ b,
    const float* __restrict__ w, float* __restrict__ sum_out,
    float* __restrict__ ln_out, ushort* __restrict__ lnb) {
  int t = blockIdx.x, tid = threadIdx.x;
  float4 x = reinterpret_cast<const float4*>(a + (size_t)t*HH)[tid];
  float4 y = reinterpret_cast<const float4*>(b + (size_t)t*HH)[tid];
  x.x += y.x; x.y += y.y; x.z += y.z; x.w += y.w;
  float ss = x.x*x.x + x.y*x.y + x.z*x.z + x.w*x.w;
  #pragma unroll
  for (int off = 1; off < 64; off <<= 1) ss += __shfl_xor(ss, off);
  __shared__ float wsum[4];
  int wid = tid >> 6, lane = tid & 63;
  if (lane == 0) wsum[wid] = ss;
  __syncthreads();
  float tot = wsum[0] + wsum[1] + wsum[2] + wsum[3];
  float r = rsqrtf(tot * (1.0f/HH) + EPS_);
  reinterpret_cast<float4*>(sum_out + (size_t)t*HH)[tid] = x;
  float4 wl = reinterpret_cast<const float4*>(w)[tid];
  float4 o = make_float4(x.x*r*wl.x, x.y*r*wl.y, x.z*r*wl.z, x.w*r*wl.w);
  reinterpret_cast<float4*>(ln_out + (size_t)t*HH)[tid] = o;
  ushort4 ub;
  ub.x = f2bf(o.x); ub.y = f2bf(o.y); ub.z = f2bf(o.z); ub.w = f2bf(o.w);
  int dst = ((tid >> 3) << 5) + ((tid & 3) << 3) + (((tid >> 2) & 1) << 2);
  *(ushort4*)(lnb + (size_t)t * HH + dst) = ub;
}

// =====================================================================
// per-(t,head) QK RMSNorm + RoPE, in-place (f32)
// =====================================================================
__global__ __launch_bounds__(256) void qk_norm_rope_kernel(
    float* __restrict__ qkv, const float* __restrict__ qw,
    const float* __restrict__ kw, const int* __restrict__ pos) {
  int t = blockIdx.x;
  int hh = blockIdx.y * 4 + (threadIdx.x >> 6);
  int lane = threadIdx.x & 63;
  float* p = qkv + (size_t)t * QKV_W + hh * HDIM;
  float x = p[lane];
  float ss = x * x;
  #pragma unroll
  for (int off = 1; off < 64; off <<= 1) ss += __shfl_xor(ss, off);
  float r = rsqrtf(ss * (1.0f/HDIM) + EPS_);
  float wv = (hh < NHEADS ? qw : kw)[lane];
  float xn = x * r * wv;
  float partner = __shfl_xor(xn, 16);
  float out = xn;
  if (lane < 32) {
    int i = lane & 15;
    float inv = powf(10000.0f, -(float)i / 16.0f);
    float ang = (float)pos[t] * inv;
    float cv = cosf(ang), sv = sinf(ang);
    out = (lane < 16) ? (xn * cv - partner * sv) : (partner * sv + xn * cv);
  }
  p[lane] = out;
}

// =====================================================================
// pack_KV: rope'd K -> A-tile images; V -> B-tile images. grid (T/32, NKVH)
// =====================================================================
__global__ __launch_bounds__(256) void pack_KV_kernel(
    const float* __restrict__ qkv, ushort* __restrict__ Kpk,
    ushort* __restrict__ Vpk) {
  __shared__ ushort kimg[2048];
  __shared__ ushort vimg[2048];
  int tid = threadIdx.x;
  int kt = blockIdx.x, kvh = blockIdx.y;
  {
    int c = tid >> 7, t2 = tid & 127;
    int g = t2 & 3, r = t2 >> 2;
    const float* kp = qkv + (size_t)(kt*32 + r) * QKV_W + NHEADS*HDIM + kvh*HDIM + 32*c + 4*g;
    float4 h0 = *(const float4*)kp;
    float4 h1 = *(const float4*)(kp + 16);
    short8 v;
    v[0]=(short)f2bf(h0.x); v[1]=(short)f2bf(h0.y); v[2]=(short)f2bf(h0.z); v[3]=(short)f2bf(h0.w);
    v[4]=(short)f2bf(h1.x); v[5]=(short)f2bf(h1.y); v[6]=(short)f2bf(h1.z); v[7]=(short)f2bf(h1.w);
    *(short8*)(kimg + c*1024 + (g*32 + (r^g))*8) = v;
  }
  stage_B_tile(qkv + (size_t)(NHEADS+NKVH)*HDIM + (size_t)kvh*HDIM, QKV_W, kt*32, 0, vimg, tid);
  __syncthreads();
  size_t toff = ((size_t)(kvh * (TT/32) + kt)) * 2048;
  *(short8*)(Kpk + toff + tid * 8) = *(const short8*)(kimg + tid * 8);
  *(short8*)(Vpk + toff + tid * 8) = *(const short8*)(vimg + tid * 8);
}

// =====================================================================
// Attention v3 (r12 verified): split-KV + fixed-max log2 softmax.
// =====================================================================
__global__ __launch_bounds__(256) void attn_v3_kernel(
    const float* __restrict__ qkv, const ushort* __restrict__ Kpk,
    const ushort* __restrict__ Vpk, ushort* __restrict__ ob,
    float* __restrict__ po, float* __restrict__ pl) {
  __shared__ ushort Ks[3][2048];
  __shared__ ushort Vs[3][2048];
  int tid = threadIdx.x;
  int wid = tid >> 6, lane = tid & 63;
  int lg = lane >> 4, lr = lane & 15;
  int h = blockIdx.y;
  int f = blockIdx.x;
  int g = 0;
  while (f >= 4 * (g + 1) * (g + 2)) ++g;
  int r_ = f - 4 * g * (g + 1);
  int ns = g + 1;
  int qb = 8 * g + r_ / ns;
  int s = r_ % ns;
  int tiles_total = 2 * qb + 2;
  int per = (tiles_total + ns - 1) / ns;
  int lo = s * per;
  int nloc = min(per, tiles_total - lo);
  int kvh = h >> 2;
  int q0 = qb * 64 + wid * 16;
  int qg = q0 + lr;
  const float SCL = 0.125f * 1.44269504f;
  const float FM = 16.0f;

  const float* qrow = qkv + (size_t)qg * QKV_W + h * HDIM;
  short8 qfr[2];
  #pragma unroll
  for (int c = 0; c < 2; ++c) {
    float4 a = *(const float4*)(qrow + 32*c + 4*lg);
    float4 b = *(const float4*)(qrow + 32*c + 4*lg + 16);
    short8 v;
    v[0]=(short)f2bf(a.x*SCL); v[1]=(short)f2bf(a.y*SCL); v[2]=(short)f2bf(a.z*SCL); v[3]=(short)f2bf(a.w*SCL);
    v[4]=(short)f2bf(b.x*SCL); v[5]=(short)f2bf(b.y*SCL); v[6]=(short)f2bf(b.z*SCL); v[7]=(short)f2bf(b.w*SCL);
    qfr[c] = v;
  }

  const ushort* ksrc = Kpk + (size_t)(kvh * (TT/32) + lo) * 2048 + wid * 512 + lane * 8;
  const ushort* vsrc = Vpk + (size_t)(kvh * (TT/32) + lo) * 2048 + wid * 512 + lane * 8;

  f32x4 o_acc[4] = {};
  float l_st = 0.f;

  auto issue = [&](int tt) {
    int b = tt % 3;
    gload16(ksrc + (size_t)tt * 2048, &Ks[b][wid * 512]);
    gload16(vsrc + (size_t)tt * 2048, &Vs[b][wid * 512]);
  };
  issue(0);
  if (nloc > 1) issue(1);
  for (int tt = 0; tt < nloc; ++tt) {
    if (tt < nloc - 1) asm volatile("s_waitcnt vmcnt(2)" ::: "memory");
    else               asm volatile("s_waitcnt vmcnt(0)" ::: "memory");
    __builtin_amdgcn_s_barrier();
    if (tt + 2 < nloc) issue(tt + 2);
    int t = lo + tt;
    if (t * 32 > q0 + 15) continue;
    int cb = tt % 3;
    f32x4 st[2];
    #pragma unroll
    for (int n = 0; n < 2; ++n) {
      short8 kf0 = *(const short8*)(&Ks[cb][(lg*32 + ((16*n + lr) ^ lg)) * 8]);
      short8 kf1 = *(const short8*)(&Ks[cb][1024 + (lg*32 + ((16*n + lr) ^ lg)) * 8]);
      f32x4 z = {};
      z = __builtin_amdgcn_mfma_f32_16x16x32_bf16(kf0, qfr[0], z, 0, 0, 0);
      st[n] = __builtin_amdgcn_mfma_f32_16x16x32_bf16(kf1, qfr[1], z, 0, 0, 0);
    }
    float p[2][4];
    float psum = 0.f;
    if (t * 32 + 31 <= q0) {
      #pragma unroll
      for (int n = 0; n < 2; ++n)
        #pragma unroll
        for (int i = 0; i < 4; ++i) {
          float pv = exp2f(st[n][i] - FM);
          p[n][i] = pv; psum += pv;
        }
    } else {
      #pragma unroll
      for (int n = 0; n < 2; ++n)
        #pragma unroll
        for (int i = 0; i < 4; ++i) {
          int kvg = t*32 + 16*n + 4*lg + i;
          float pv = (kvg <= qg) ? exp2f(st[n][i] - FM) : 0.f;
          p[n][i] = pv; psum += pv;
        }
    }
    psum += __shfl_xor(psum, 16);
    psum += __shfl_xor(psum, 32);
    l_st += psum;
    union { unsigned u[4]; short8 s8; } pu;
    asm volatile("v_cvt_pk_bf16_f32 %0, %1, %2" : "=v"(pu.u[0]) : "v"(p[0][0]), "v"(p[0][1]));
    asm volatile("v_cvt_pk_bf16_f32 %0, %1, %2" : "=v"(pu.u[1]) : "v"(p[0][2]), "v"(p[0][3]));
    asm volatile("v_cvt_pk_bf16_f32 %0, %1, %2" : "=v"(pu.u[2]) : "v"(p[1][0]), "v"(p[1][1]));
    asm volatile("v_cvt_pk_bf16_f32 %0, %1, %2" : "=v"(pu.u[3]) : "v"(p[1][2]), "v"(p[1][3]));
    short8 pa = pu.s8;
    #pragma unroll
    for (int nd = 0; nd < 4; ++nd) {
      short8 vf = read_b_frag(&Vs[cb][0], lg, 16*nd + lr);
      o_acc[nd] = __builtin_amdgcn_mfma_f32_16x16x32_bf16(pa, vf, o_acc[nd], 0, 0, 0);
    }
  }

  if (ns == 1) {
    #pragma unroll
    for (int i = 0; i < 4; ++i) {
      float lrow = __shfl(l_st, 4*lg + i);
      float inv = 1.0f / lrow;
      int row = q0 + 4*lg + i;
      ushort* op = ob + (size_t)row * (NHEADS*HDIM) + h * HDIM;
      #pragma unroll
      for (int nd = 0; nd < 4; ++nd) {
        int pcol = ((nd >> 1) << 5) + ((lr >> 2) << 3) + ((nd & 1) << 2) + (lr & 3);
        op[pcol] = f2bf(o_acc[nd][i] * inv);
      }
    }
  } else {
    float* pob = po + ((size_t)f * NHEADS + h) * 4096;
    #pragma unroll
    for (int nd = 0; nd < 4; ++nd)
      #pragma unroll
      for (int i = 0; i < 4; ++i)
        pob[(wid * 16 + lg * 4 + i) * 64 + 16 * nd + lr] = o_acc[nd][i];
    if (lg == 0)
      pl[((size_t)f * NHEADS + h) * 64 + wid * 16 + lr] = l_st;
  }
}

// =====================================================================
// attn combine (r12 verified)
// =====================================================================
__global__ __launch_bounds__(256) void attn_combine_kernel(
    const float* __restrict__ po, const float* __restrict__ pl,
    ushort* __restrict__ ob) {
  int h = blockIdx.x;
  int qb = 8 + blockIdx.y;
  int g = qb >> 3;
  int ns = g + 1;
  int f0 = 4 * g * (g + 1) + (qb - 8 * g) * ns;
  int tid = threadIdx.x;
  int r = tid >> 2, c = tid & 3;
  float acc[16] = {};
  float lsum = 0.f;
  for (int s = 0; s < ns; ++s) {
    size_t base = ((size_t)(f0 + s) * NHEADS + h) * 4096 + r * 64 + c * 16;
    #pragma unroll
    for (int j = 0; j < 4; ++j) {
      float4 v = *(const float4*)(po + base + j * 4);
      acc[j*4+0] += v.x; acc[j*4+1] += v.y; acc[j*4+2] += v.z; acc[j*4+3] += v.w;
    }
    lsum += pl[((size_t)(f0 + s) * NHEADS + h) * 64 + r];
  }
  float inv = 1.0f / lsum;
  int row = qb * 64 + r;
  ushort* op = ob + (size_t)row * (NHEADS*HDIM) + h * HDIM + (c >> 1) * 32 + (c & 1) * 4;
  #pragma unroll
  for (int a = 0; a < 4; ++a) {
    ushort4 u;
    u.x = f2bf(acc[a*4+0] * inv); u.y = f2bf(acc[a*4+1] * inv);
    u.z = f2bf(acc[a*4+2] * inv); u.w = f2bf(acc[a*4+3] * inv);
    *(ushort4*)(op + a * 8) = u;
  }
}

// =====================================================================
// router: wave-parallel (r8 verified)
// =====================================================================
__global__ __launch_bounds__(256) void router_kernel(
    const float* __restrict__ hln, const float* __restrict__ Wg,
    const float* __restrict__ bias, int* __restrict__ sel_e,
    float* __restrict__ sel_w) {
  __shared__ float hid[4][HH];
  int tid = threadIdx.x, wid = tid >> 6, lane = tid & 63;
  int t = blockIdx.x * 4 + wid;
  const float4* src = (const float4*)(hln + (size_t)t * HH);
  float4* dst = (float4*)hid[wid];
  #pragma unroll
  for (int j = 0; j < 4; ++j) dst[j * 64 + lane] = src[j * 64 + lane];
  int e = lane & 31, half = lane >> 5;
  const float* wp = Wg + (size_t)(half * 512) * NEXP + e;
  const float* hp = hid[wid] + half * 512;
  float p = 0.f;
  #pragma unroll 8
  for (int h = 0; h < 512; ++h) p += hp[h] * wp[(size_t)h * NEXP];
  p += __shfl_xor(p, 32);
  float sc = 1.0f / (1.0f + expf(-p));
  float sfc = sc + bias[e];
  float m1 = sfc, m2 = -1e30f;
  #pragma unroll
  for (int off = 1; off <= 4; off <<= 1) {
    float om1 = __shfl_xor(m1, off), om2 = __shfl_xor(m2, off);
    float hi_ = fmaxf(m1, om1);
    float lo_ = fmaxf(fminf(m1, om1), fmaxf(m2, om2));
    m1 = hi_; m2 = lo_;
  }
  float gs = m1 + m2;
  float gv[4] = {__shfl(gs, 0), __shfl(gs, 8), __shfl(gs, 16), __shfl(gs, 24)};
  int g1 = 0; float b1 = gv[0];
  #pragma unroll
  for (int g = 1; g < 4; ++g) if (gv[g] > b1) { b1 = gv[g]; g1 = g; }
  int g2 = -1; float b2 = -1e30f;
  #pragma unroll
  for (int g = 0; g < 4; ++g) if (g != g1 && gv[g] > b2) { b2 = gv[g]; g2 = g; }
  bool keep = ((e >> 3) == g1) || ((e >> 3) == g2);
  float cand = keep ? sfc : -1e30f;
  int ids[4]; float wv[4]; float wsum = 0.f;
  #pragma unroll
  for (int s = 0; s < 4; ++s) {
    float v = cand; int ix = e;
    #pragma unroll
    for (int off = 1; off < 64; off <<= 1) {
      float ov = __shfl_xor(v, off); int oix = __shfl_xor(ix, off);
      if (ov > v || (ov == v && oix < ix)) { v = ov; ix = oix; }
    }
    ids[s] = ix;
    if (e == ix) cand = -1e30f;
    float w = __shfl(sc, ix);
    wv[s] = w; wsum += w;
  }
  if (lane == 0) {
    #pragma unroll
    for (int s = 0; s < 4; ++s) {
      sel_e[t * 4 + s] = ids[s];
      sel_w[t * 4 + s] = wv[s] / wsum;
    }
  }
}

__global__ __launch_bounds__(256) void count_kernel(
    const int* __restrict__ sel_e, int* __restrict__ counts) {
  int e = blockIdx.x, tid = threadIdx.x;
  int c = 0;
  for (int i = tid; i < TT * TOPK_; i += 256) c += (sel_e[i] == e);
  #pragma unroll
  for (int off = 1; off < 64; off <<= 1) c += __shfl_xor(c, off);
  __shared__ int wsum[4];
  if ((tid & 63) == 0) wsum[tid >> 6] = c;
  __syncthreads();
  if (tid == 0) counts[e] = wsum[0] + wsum[1] + wsum[2] + wsum[3];
}

// scan + flat slot-block table (BM=32 granularity)
__global__ void scan_kernel(const int* __restrict__ counts,
                            int* __restrict__ offs, int* __restrict__ cursor,
                            int* __restrict__ sb_e, int* __restrict__ sb_base,
                            int* __restrict__ nsb) {
  if (threadIdx.x == 0) {
    int acc = 0, n = 0;
    for (int e = 0; e < NEXP; ++e) {
      offs[e] = acc; cursor[e] = acc;
      int c = counts[e];
      for (int b = 0; b < c; b += 32) { sb_e[n] = e; sb_base[n] = b; ++n; }
      acc += c;
    }
    *nsb = n;
  }
}

__global__ void scatter_kernel(const int* __restrict__ sel_e,
                               int* __restrict__ cursor, int* __restrict__ perm,
                               int* __restrict__ ipos) {
  int i = blockIdx.x * 256 + threadIdx.x;
  if (i < TT * TOPK_) {
    int e = sel_e[i];
    int pos = atomicAdd(&cursor[e], 1);
    perm[pos] = i;
    ipos[i] = pos;
  }
}

// =====================================================================
// shared-expert SiLU*mul -> permuted bf16 (4 cols/thread)
// =====================================================================
__global__ __launch_bounds__(256) void silu_shared_kernel(
    const float* __restrict__ gus, ushort* __restrict__ shsb) {
  int i = blockIdx.x * 256 + threadIdx.x;
  if (i < TT * (ISHARED/4)) {
    int t = i / (ISHARED/4), k = i % (ISHARED/4);
    const float* gp = gus + (size_t)t * (2*ISHARED) + k * 4;
    float4 g4 = *(const float4*)gp;
    float4 u4 = *(const float4*)(gp + ISHARED);
    ushort4 r;
    r.x = f2bf(g4.x / (1.f + expf(-g4.x)) * u4.x);
    r.y = f2bf(g4.y / (1.f + expf(-g4.y)) * u4.y);
    r.z = f2bf(g4.z / (1.f + expf(-g4.z)) * u4.z);
    r.w = f2bf(g4.w / (1.f + expf(-g4.w)) * u4.w);
    int pdst = ((k >> 3) << 5) + ((k & 3) << 3) + (((k >> 2) & 1) << 2);
    *(ushort4*)(shsb + (size_t)t * ISHARED + pdst) = r;
  }
}

// =====================================================================
// final combine (bf16 partial)
// =====================================================================
__global__ __launch_bounds__(256) void final_combine_kernel(
    const ushort* __restrict__ partialb, const float* __restrict__ sel_w,
    const int* __restrict__ ipos, const float* __restrict__ shared_out,
    float* __restrict__ out_hidden) {
  int t = blockIdx.x, tid = threadIdx.x;
  float w0 = sel_w[t*4], w1 = sel_w[t*4+1], w2 = sel_w[t*4+2], w3 = sel_w[t*4+3];
  int p0 = ipos[t*4], p1 = ipos[t*4+1], p2 = ipos[t*4+2], p3 = ipos[t*4+3];
  ushort4 a0 = *(const ushort4*)(partialb + (size_t)p0*HH + tid*4);
  ushort4 a1 = *(const ushort4*)(partialb + (size_t)p1*HH + tid*4);
  ushort4 a2 = *(const ushort4*)(partialb + (size_t)p2*HH + tid*4);
  ushort4 a3 = *(const ushort4*)(partialb + (size_t)p3*HH + tid*4);
  float4 sh = reinterpret_cast<const float4*>(shared_out + (size_t)t*HH)[tid];
  float4 r;
  r.x = (w0*bf2f(a0.x) + w1*bf2f(a1.x) + w2*bf2f(a2.x) + w3*bf2f(a3.x)) + sh.x;
  r.y = (w0*bf2f(a0.y) + w1*bf2f(a1.y) + w2*bf2f(a2.y) + w3*bf2f(a3.y)) + sh.y;
  r.z = (w0*bf2f(a0.z) + w1*bf2f(a1.z) + w2*bf2f(a2.z) + w3*bf2f(a3.z)) + sh.z;
  r.w = (w0*bf2f(a0.w) + w1*bf2f(a1.w) + w2*bf2f(a2.w) + w3*bf2f(a3.w)) + sh.w;
  reinterpret_cast<float4*>(out_hidden + (size_t)t*HH)[tid] = r;
}

// =====================================================================
extern "C" void kernel_launch(void* const* d_in, const int* in_sizes, int n_in,
                              void* d_out, int out_size, void* d_ws, size_t ws_size,
                              hipStream_t stream) {
  const float* hidden   = (const float*)d_in[0];
  const float* residual = (const float*)d_in[1];
  const float* in_ln_w  = (const float*)d_in[2];
  const float* post_ln_w= (const float*)d_in[3];
  const float* q_norm_w = (const float*)d_in[4];
  const float* k_norm_w = (const float*)d_in[5];
  const float* Wqkv     = (const float*)d_in[6];
  const float* Wo       = (const float*)d_in[7];
  const float* Wg       = (const float*)d_in[8];
  const float* gate_bias= (const float*)d_in[9];
  const float* Wgu      = (const float*)d_in[10];
  const float* Wd       = (const float*)d_in[11];
  const float* Wgu_sh   = (const float*)d_in[12];
  const float* Wd_sh    = (const float*)d_in[13];
  const int*   positions= (const int*)d_in[14];
  float* out = (float*)d_out;

  float* f = (float*)d_ws;
  size_t off = 0;
  float* R_A   = f + off; off += (size_t)TT*HH;
  float* HLN   = f + off; off += (size_t)TT*HH;
  float* QKV   = f + off; off += (size_t)TT*QKV_W;        // reused as gus
  float* OATT  = f + off; off += (size_t)TT*HH;           // DSH output (shared_out)
  float* HLN2  = f + off; off += (size_t)TT*HH;
  float* SELW  = f + off; off += (size_t)TT*TOPK_;
  float* PO    = f + off; off += (size_t)NSPLITS*NHEADS*4096;  // attn partial O
  float* PL    = f + off; off += (size_t)NSPLITS*NHEADS*64;    // attn partial l
  ushort* HLNB  = (ushort*)(f + off); off += (size_t)TT*HH/2;
  ushort* HLN2B = (ushort*)(f + off); off += (size_t)TT*HH/2;
  ushort* OATTB = (ushort*)(f + off); off += (size_t)TT*HH/2;
  ushort* SHSB  = (ushort*)(f + off); off += (size_t)TT*ISHARED/2;
  ushort* KPK   = (ushort*)(f + off); off += (size_t)NKVH*(TT/32)*2048/2;
  ushort* VPK   = (ushort*)(f + off); off += (size_t)NKVH*(TT/32)*2048/2;
  ushort* ACTB  = (ushort*)(f + off); off += (size_t)(TT*TOPK_ + 128)*IMID/2;
  ushort* PARTB = (ushort*)(f + off); off += (size_t)TT*TOPK_*HH/2;
  ushort* PK_QKV = (ushort*)(f + off); off += (size_t)HH*QKV_W/2;
  ushort* PK_WO  = (ushort*)(f + off); off += (size_t)HH*HH/2;
  ushort* PK_WGU = (ushort*)(f + off); off += (size_t)NEXP*HH*(2*IMID)/2;
  ushort* PK_WD  = (ushort*)(f + off); off += (size_t)NEXP*IMID*HH/2;
  ushort* PK_GUSH= (ushort*)(f + off); off += (size_t)HH*(2*ISHARED)/2;
  ushort* PK_DSH = (ushort*)(f + off); off += (size_t)ISHARED*HH/2;
  int* ibase   = (int*)(f + off);
  int* SELE    = ibase;
  int* PERM    = ibase + TT*TOPK_;
  int* IPOS    = ibase + 2*TT*TOPK_;
  int* COUNTS  = ibase + 3*TT*TOPK_;
  int* OFFS    = COUNTS + NEXP;
  int* CURSOR  = OFFS + NEXP;
  int* SB_E    = CURSOR + NEXP;
  int* SB_BASE = SB_E + MAXSB;
  int* NSB     = SB_BASE + MAXSB;

  // 0. pack all weights to bf16 tile images
  pack_B_kernel<<<dim3(QKV_W/64, HH/32), 256, 0, stream>>>(Wqkv, PK_QKV, QKV_W);
  pack_B_kernel<<<dim3(HH/64, HH/32), 256, 0, stream>>>(Wo, PK_WO, HH);
  pack_B_kernel<<<dim3((2*IMID)/64, NEXP*HH/32), 256, 0, stream>>>(Wgu, PK_WGU, 2*IMID);
  pack_B_kernel<<<dim3(HH/64, NEXP*IMID/32), 256, 0, stream>>>(Wd, PK_WD, HH);
  pack_B_kernel<<<dim3((2*ISHARED)/64, HH/32), 256, 0, stream>>>(Wgu_sh, PK_GUSH, 2*ISHARED);
  pack_B_kernel<<<dim3(HH/64, ISHARED/32), 256, 0, stream>>>(Wd_sh, PK_DSH, HH);

  // 1. pipeline
  add_rms_kernel<<<TT, 256, 0, stream>>>(hidden, residual, in_ln_w, R_A, HLN, HLNB);
  gemm64_bb<<<dim3(QKV_W/64, TT/64), 256, 0, stream>>>(HLNB, PK_QKV, QKV, TT, QKV_W, HH);
  qk_norm_rope_kernel<<<dim3(TT, 5), 256, 0, stream>>>(QKV, q_norm_w, k_norm_w, positions);
  pack_KV_kernel<<<dim3(TT/32, NKVH), 256, 0, stream>>>(QKV, KPK, VPK);
  attn_v3_kernel<<<dim3(NSPLITS, NHEADS), 256, 0, stream>>>(QKV, KPK, VPK, OATTB, PO, PL);
  attn_combine_kernel<<<dim3(NHEADS, 24), 256, 0, stream>>>(PO, PL, OATTB);
  gemm64_bb<<<dim3(HH/64, TT/64), 256, 0, stream>>>(OATTB, PK_WO, HLN, TT, HH, HH);
  add_rms_kernel<<<TT, 256, 0, stream>>>(HLN, R_A, post_ln_w, out + (size_t)TT*HH, HLN2, HLN2B);
  router_kernel<<<TT/4, 256, 0, stream>>>(HLN2, Wg, gate_bias, SELE, SELW);
  count_kernel<<<NEXP, 256, 0, stream>>>(SELE, COUNTS);
  scan_kernel<<<1, 64, 0, stream>>>(COUNTS, OFFS, CURSOR, SB_E, SB_BASE, NSB);
  scatter_kernel<<<(TT*TOPK_ + 255)/256, 256, 0, stream>>>(SELE, CURSOR, PERM, IPOS);
  moe_up_pk<<<dim3(MAXSB, 3), 256, 0, stream>>>(HLN2B, PK_WGU, PERM, OFFS, COUNTS, SB_E, SB_BASE, NSB, ACTB);
  moe_down_pk<<<dim3(MAXSB, HH/64), 256, 0, stream>>>(ACTB, PK_WD, OFFS, COUNTS, SB_E, SB_BASE, NSB, PARTB);
  gemm64_bb<<<dim3((2*ISHARED)/64, TT/64), 256, 0, stream>>>(HLN2B, PK_GUSH, QKV, TT, 2*ISHARED, HH);
  silu_shared_kernel<<<(TT*(ISHARED/4) + 255)/256, 256, 0, stream>>>(QKV, SHSB);
  gemm64_bb<<<dim3(HH/64, TT/64), 256, 0, stream>>>(SHSB, PK_DSH, OATT, TT, HH, ISHARED);
  final_combine_kernel<<<TT, 256, 0, stream>>>(PARTB, SELW, IPOS, OATT, out);
}

// Round 18
// 299.427 us; speedup vs baseline: 1.2688x; 1.1417x over previous
//
#include <hip/hip_runtime.h>
#include <math.h>

// ---- problem constants ----
#define TT 2048
#define HH 1024
#define NHEADS 16
#define NKVH 4
#define HDIM 64
#define NEXP 32
#define TOPK_ 4
#define NGRP 4
#define IMID 384
#define ISHARED 384
#define QKV_W (24*64)   // 1536
#define EPS_ 1e-5f
#define MAXSB 288       // max slot-blocks: 8192/32 + 32 (= 8*36)
#define NSPLITS 80      // attn split-entries per head

typedef __attribute__((ext_vector_type(8))) short short8;
typedef __attribute__((ext_vector_type(4))) float f32x4;

__device__ __forceinline__ ushort f2bf(float x) {
  union { float f; unsigned u; } v; v.f = x;
  unsigned r = v.u + 0x7fffu + ((v.u >> 16) & 1u);
  return (ushort)(r >> 16);
}
__device__ __forceinline__ float bf2f(ushort u) {
  union { unsigned i; float f; } v; v.i = (unsigned)u << 16; return v.f;
}

// async global->LDS, 16B per lane; lds dst = wave-uniform base + lane*16
__device__ __forceinline__ void gload16(const void* g, void* l) {
  __builtin_amdgcn_global_load_lds(
      (const __attribute__((address_space(1))) unsigned int*)g,
      (__attribute__((address_space(3))) unsigned int*)l, 16, 0, 0);
}

// =====================================================================
// MFMA fragment layouts (16x16x32 bf16), verified rounds 1-17. See r17.
// r18: stage bodies -> __device__ fns; fused launches overlap
// independent stages (packs under attn; shared-expert GEMMs under MoE).
// =====================================================================
__device__ __forceinline__ short8 read_a_frag32(const ushort* As, int lg, int row) {
  return *(const short8*)(As + ((lg * 32 + (row ^ lg)) * 8));
}
__device__ __forceinline__ short8 read_a_frag64(const ushort* As, int lg, int row) {
  return *(const short8*)(As + ((lg * 64 + (row ^ lg)) * 8));
}
__device__ __forceinline__ short8 read_b_frag(const ushort* Bs, int lg, int col) {
  int boff = (col * 16) ^ (((col >> 3) & 7) << 4);
  return *(const short8*)((const char*)Bs + lg * 1024 + boff);
}

// B-tile staging from f32 (pack bodies only)
__device__ __forceinline__ void stage_B_tile(const float* __restrict__ B, int ldb,
                                             int k0, int col0, ushort* Bs, int tid) {
  int a = tid >> 4;
  int cG = tid & 15;
  int k = 2 * a;
  const float* p0 = B + (size_t)(k0 + k) * ldb + col0 + cG * 4;
  const float* p1 = p0 + ldb;
  float4 r0 = *(const float4*)p0;
  float4 r1 = *(const float4*)p1;
  int gg = (k & 15) >> 2;
  int slot = (k & 3) + ((k >> 4) << 2);
  float v0[4] = {r0.x, r0.y, r0.z, r0.w};
  float v1[4] = {r1.x, r1.y, r1.z, r1.w};
  char* plane = (char*)Bs + gg * 1024;
  #pragma unroll
  for (int j = 0; j < 4; ++j) {
    int c = cG * 4 + j;
    unsigned pk = (unsigned)f2bf(v0[j]) | ((unsigned)f2bf(v1[j]) << 16);
    int boff = ((c * 16) ^ (((c >> 3) & 7) << 4)) + slot * 2;
    *(unsigned*)(plane + boff) = pk;
  }
}

// ---------------------------------------------------------------------
// pack body: one 32x64 tile -> packed image. ntn passed explicitly.
// ---------------------------------------------------------------------
__device__ __forceinline__ void pack_B_body(
    const float* __restrict__ src, ushort* __restrict__ dst, int N,
    int ntn, int kt, int nt, ushort* tileB, int tid) {
  stage_B_tile(src, N, kt * 32, nt * 64, tileB, tid);
  __syncthreads();
  size_t toff = ((size_t)kt * ntn + nt) * 2048;
  *(short8*)(dst + toff + tid * 8) = *(const short8*)(tileB + tid * 8);
}

// ---------------------------------------------------------------------
// add_rms body (r17 numerics, wsum carved from smem)
// ---------------------------------------------------------------------
__device__ __forceinline__ void add_rms_body(
    const float* __restrict__ a, const float* __restrict__ b,
    const float* __restrict__ w, float* __restrict__ sum_out,
    float* __restrict__ ln_out, ushort* __restrict__ lnb,
    int t, int tid, float* wsum) {
  float4 x = reinterpret_cast<const float4*>(a + (size_t)t*HH)[tid];
  float4 y = reinterpret_cast<const float4*>(b + (size_t)t*HH)[tid];
  x.x += y.x; x.y += y.y; x.z += y.z; x.w += y.w;
  float ss = x.x*x.x + x.y*x.y + x.z*x.z + x.w*x.w;
  #pragma unroll
  for (int off = 1; off < 64; off <<= 1) ss += __shfl_xor(ss, off);
  int wid = tid >> 6, lane = tid & 63;
  if (lane == 0) wsum[wid] = ss;
  __syncthreads();
  float tot = wsum[0] + wsum[1] + wsum[2] + wsum[3];
  float r = rsqrtf(tot * (1.0f/HH) + EPS_);
  reinterpret_cast<float4*>(sum_out + (size_t)t*HH)[tid] = x;
  float4 wl = reinterpret_cast<const float4*>(w)[tid];
  float4 o = make_float4(x.x*r*wl.x, x.y*r*wl.y, x.z*r*wl.z, x.w*r*wl.w);
  reinterpret_cast<float4*>(ln_out + (size_t)t*HH)[tid] = o;
  ushort4 ub;
  ub.x = f2bf(o.x); ub.y = f2bf(o.y); ub.z = f2bf(o.z); ub.w = f2bf(o.w);
  int dst = ((tid >> 3) << 5) + ((tid & 3) << 3) + (((tid >> 2) & 1) << 2);
  *(ushort4*)(lnb + (size_t)t * HH + dst) = ub;
}

// ---------------------------------------------------------------------
// Dense GEMM body (r10-verified): BM=64, BN=64, ring-4, dist-3.
// smem: As 16KB @0, Bs 16KB @16384.
// ---------------------------------------------------------------------
__device__ __forceinline__ void gemm64_body(
    const ushort* __restrict__ Ab, const ushort* __restrict__ Bpk,
    float* __restrict__ C, int M, int N, int K, int bx, int by, char* smem) {
  ushort (*As)[2048] = (ushort(*)[2048])smem;
  ushort (*Bs)[2048] = (ushort(*)[2048])(smem + 16384);
  int tid = threadIdx.x;
  int row0 = by * 64, col0 = bx * 64;
  int ntn = N >> 6;
  int wid = tid >> 6, lane = tid & 63;
  int lg = lane >> 4, lr = lane & 15;
  int wrow = (wid >> 1) * 32, wcol = (wid & 1) * 32;
  const ushort* asrc = Ab + (size_t)(row0 + (lane ^ wid)) * K + wid * 8;
  const ushort* bsrc = Bpk + (size_t)bx * 2048 + wid * 512 + lane * 8;
  const int NT = K >> 5;
  f32x4 acc[2][2] = {};

  auto issue = [&](int tt) {
    int b = tt & 3;
    gload16(asrc + tt * 32, &As[b][wid * 512]);
    gload16(bsrc + (size_t)tt * ntn * 2048, &Bs[b][wid * 512]);
  };
  issue(0); issue(1); issue(2);
  for (int t = 0; t < NT; ++t) {
    int ahead = NT - 1 - t;
    if (ahead >= 2)      asm volatile("s_waitcnt vmcnt(4)" ::: "memory");
    else if (ahead == 1) asm volatile("s_waitcnt vmcnt(2)" ::: "memory");
    else                 asm volatile("s_waitcnt vmcnt(0)" ::: "memory");
    __builtin_amdgcn_s_barrier();
    if (t + 3 < NT) issue(t + 3);
    int cb = t & 3;
    short8 af0 = read_a_frag64(&As[cb][0], lg, wrow + lr);
    short8 af1 = read_a_frag64(&As[cb][0], lg, wrow + 16 + lr);
    #pragma unroll
    for (int nn = 0; nn < 2; ++nn) {
      short8 bf_ = read_b_frag(&Bs[cb][0], lg, wcol + nn * 16 + lr);
      acc[0][nn] = __builtin_amdgcn_mfma_f32_16x16x32_bf16(af0, bf_, acc[0][nn], 0, 0, 0);
      acc[1][nn] = __builtin_amdgcn_mfma_f32_16x16x32_bf16(af1, bf_, acc[1][nn], 0, 0, 0);
    }
  }
  #pragma unroll
  for (int mm = 0; mm < 2; ++mm)
    #pragma unroll
    for (int nn = 0; nn < 2; ++nn) {
      int row = row0 + wrow + mm * 16 + lg * 4;
      int col = col0 + wcol + nn * 16 + lr;
      #pragma unroll
      for (int i = 0; i < 4; ++i)
        C[(size_t)(row + i) * N + col] = acc[mm][nn][i];
    }
}

__global__ __launch_bounds__(256) void gemm64_bb(
    const ushort* __restrict__ Ab, const ushort* __restrict__ Bpk,
    float* __restrict__ C, int M, int N, int K) {
  __shared__ char smem[32768];
  gemm64_body(Ab, Bpk, C, M, N, K, blockIdx.x, blockIdx.y, smem);
}

// ---------------------------------------------------------------------
// MoE up-proj v5 body (r17-verified 60us): reg-direct, peeled, no LDS.
// ---------------------------------------------------------------------
__device__ __forceinline__ void moe_up_body(
    const ushort* __restrict__ hln2b, const ushort* __restrict__ Wpk,
    const int* __restrict__ perm, const int* __restrict__ offs,
    const int* __restrict__ counts, const int* __restrict__ sb_e,
    const int* __restrict__ sb_base, const int* __restrict__ nsb,
    ushort* __restrict__ actb, int b, int by) {
  int sb = ((b & 7) * 36) + (b >> 3);
  if (sb >= *nsb) return;
  int e = sb_e[sb];
  int base = sb_base[sb];
  int start = offs[e];
  int nt = min(32, counts[e] - base);
  int tid = threadIdx.x;
  int wid = tid >> 6, lane = tid & 63;
  int lg = lane >> 4, lr = lane & 15;
  int bz = by * 2 + (wid >> 1);   // 0..5
  int wcol = (wid & 1) * 32;
  int tok0 = perm[start + base + min(lr, nt - 1)] >> 2;
  int tok1 = perm[start + base + min(16 + lr, nt - 1)] >> 2;
  const ushort* a0p = hln2b + (size_t)tok0 * HH + lg * 8;
  const ushort* a1p = hln2b + (size_t)tok1 * HH + lg * 8;
  int c0 = wcol + lr, c1 = wcol + 16 + lr;
  int sw0 = (c0 * 16) ^ (((c0 >> 3) & 7) << 4);
  int sw1 = (c1 * 16) ^ (((c1 >> 3) & 7) << 4);
  const char* gbase = (const char*)Wpk + ((size_t)(e * 32) * 12 + bz) * 4096 + lg * 1024;
  const char* ubase = gbase + (size_t)6 * 4096;
  const size_t bstep = (size_t)12 * 4096;
  f32x4 accg[2][2] = {}, accu[2][2] = {};
  short8 a0c = *(const short8*)(a0p);
  short8 a1c = *(const short8*)(a1p);
  short8 g0c = *(const short8*)(gbase + sw0);
  short8 g1c = *(const short8*)(gbase + sw1);
  short8 u0c = *(const short8*)(ubase + sw0);
  short8 u1c = *(const short8*)(ubase + sw1);
  #pragma unroll 4
  for (int t = 0; t < 31; ++t) {
    const char* gb = gbase + (size_t)(t + 1) * bstep;
    const char* ub = ubase + (size_t)(t + 1) * bstep;
    short8 a0n = *(const short8*)(a0p + (t + 1) * 32);
    short8 a1n = *(const short8*)(a1p + (t + 1) * 32);
    short8 g0n = *(const short8*)(gb + sw0);
    short8 g1n = *(const short8*)(gb + sw1);
    short8 u0n = *(const short8*)(ub + sw0);
    short8 u1n = *(const short8*)(ub + sw1);
    accg[0][0] = __builtin_amdgcn_mfma_f32_16x16x32_bf16(a0c, g0c, accg[0][0], 0, 0, 0);
    accg[0][1] = __builtin_amdgcn_mfma_f32_16x16x32_bf16(a0c, g1c, accg[0][1], 0, 0, 0);
    accg[1][0] = __builtin_amdgcn_mfma_f32_16x16x32_bf16(a1c, g0c, accg[1][0], 0, 0, 0);
    accg[1][1] = __builtin_amdgcn_mfma_f32_16x16x32_bf16(a1c, g1c, accg[1][1], 0, 0, 0);
    accu[0][0] = __builtin_amdgcn_mfma_f32_16x16x32_bf16(a0c, u0c, accu[0][0], 0, 0, 0);
    accu[0][1] = __builtin_amdgcn_mfma_f32_16x16x32_bf16(a0c, u1c, accu[0][1], 0, 0, 0);
    accu[1][0] = __builtin_amdgcn_mfma_f32_16x16x32_bf16(a1c, u0c, accu[1][0], 0, 0, 0);
    accu[1][1] = __builtin_amdgcn_mfma_f32_16x16x32_bf16(a1c, u1c, accu[1][1], 0, 0, 0);
    a0c = a0n; a1c = a1n; g0c = g0n; g1c = g1n; u0c = u0n; u1c = u1n;
  }
  accg[0][0] = __builtin_amdgcn_mfma_f32_16x16x32_bf16(a0c, g0c, accg[0][0], 0, 0, 0);
  accg[0][1] = __builtin_amdgcn_mfma_f32_16x16x32_bf16(a0c, g1c, accg[0][1], 0, 0, 0);
  accg[1][0] = __builtin_amdgcn_mfma_f32_16x16x32_bf16(a1c, g0c, accg[1][0], 0, 0, 0);
  accg[1][1] = __builtin_amdgcn_mfma_f32_16x16x32_bf16(a1c, g1c, accg[1][1], 0, 0, 0);
  accu[0][0] = __builtin_amdgcn_mfma_f32_16x16x32_bf16(a0c, u0c, accu[0][0], 0, 0, 0);
  accu[0][1] = __builtin_amdgcn_mfma_f32_16x16x32_bf16(a0c, u1c, accu[0][1], 0, 0, 0);
  accu[1][0] = __builtin_amdgcn_mfma_f32_16x16x32_bf16(a1c, u0c, accu[1][0], 0, 0, 0);
  accu[1][1] = __builtin_amdgcn_mfma_f32_16x16x32_bf16(a1c, u1c, accu[1][1], 0, 0, 0);
  #pragma unroll
  for (int mm = 0; mm < 2; ++mm)
    #pragma unroll
    for (int nn = 0; nn < 2; ++nn) {
      int pcol = bz * 64 + wcol + ((lr >> 2) << 3) + (nn << 2) + (lr & 3);
      #pragma unroll
      for (int i = 0; i < 4; ++i) {
        int rr = mm * 16 + lg * 4 + i;
        if (rr < nt) {
          float gv = accg[mm][nn][i], uv = accu[mm][nn][i];
          float av = gv / (1.f + expf(-gv)) * uv;
          actb[(size_t)(start + base + rr) * IMID + pcol] = f2bf(av);
        }
      }
    }
}

// ---------------------------------------------------------------------
// MoE down-proj v3 body (r13-verified): LDS ring-3. smem: As 6KB, Bs 12KB.
// ---------------------------------------------------------------------
__device__ __forceinline__ void moe_down_body(
    const ushort* __restrict__ actb, const ushort* __restrict__ Wpk,
    const int* __restrict__ offs, const int* __restrict__ counts,
    const int* __restrict__ sb_e, const int* __restrict__ sb_base,
    const int* __restrict__ nsb, ushort* __restrict__ partialb,
    int b, int bz, char* smem) {
  int sb = ((b & 7) * 36) + (b >> 3);
  if (sb >= *nsb) return;
  ushort (*As)[1024] = (ushort(*)[1024])smem;
  ushort (*Bs)[2048] = (ushort(*)[2048])(smem + 6144);
  int e = sb_e[sb];
  int base = sb_base[sb];
  int start = offs[e];
  int nt = min(32, counts[e] - base);
  int tid = threadIdx.x;
  int col0 = bz * 64;
  int wid = tid >> 6, lane = tid & 63;
  int lg = lane >> 4, lr = lane & 15;
  int wrow = (wid >> 1) * 16, wcol = (wid & 1) * 32;
  const ushort* bt0 = Wpk + ((size_t)(e * 12) * 16 + bz) * 2048 + wid * 512 + lane * 8;
  int ga = wid * 2 + (lane >> 5);
  const ushort* asrcA = actb + (size_t)(start + base + ((lane & 31) ^ ga)) * IMID + ga * 8;
  const int NT = IMID >> 5;   // 12
  f32x4 acc[2] = {};

  auto issue = [&](int tt) {
    int bb = tt % 3;
    if (wid < 2) gload16(asrcA + tt * 32, &As[bb][wid * 512]);
    gload16(bt0 + (size_t)tt * 16 * 2048, &Bs[bb][wid * 512]);
  };
  issue(0); issue(1);
  for (int t = 0; t < NT; ++t) {
    if (t < NT - 1) {
      if (wid < 2) asm volatile("s_waitcnt vmcnt(2)" ::: "memory");
      else         asm volatile("s_waitcnt vmcnt(1)" ::: "memory");
    } else {
      asm volatile("s_waitcnt vmcnt(0)" ::: "memory");
    }
    __builtin_amdgcn_s_barrier();
    if (t + 2 < NT) issue(t + 2);
    int cb = t % 3;
    short8 af = read_a_frag32(&As[cb][0], lg, wrow + lr);
    #pragma unroll
    for (int nn = 0; nn < 2; ++nn) {
      short8 bf_ = read_b_frag(&Bs[cb][0], lg, wcol + nn * 16 + lr);
      acc[nn] = __builtin_amdgcn_mfma_f32_16x16x32_bf16(af, bf_, acc[nn], 0, 0, 0);
    }
  }
  #pragma unroll
  for (int nn = 0; nn < 2; ++nn)
    #pragma unroll
    for (int i = 0; i < 4; ++i) {
      int rr = wrow + lg * 4 + i;
      if (rr < nt)
        partialb[(size_t)(start + base + rr) * HH + col0 + wcol + nn * 16 + lr] = f2bf(acc[nn][i]);
    }
}

// ---------------------------------------------------------------------
// Attention v3 body (r12-verified). smem: Ks 12KB @0, Vs 12KB @12288.
// ---------------------------------------------------------------------
__device__ __forceinline__ void attn_body(
    const float* __restrict__ qkv, const ushort* __restrict__ Kpk,
    const ushort* __restrict__ Vpk, ushort* __restrict__ ob,
    float* __restrict__ po, float* __restrict__ pl, int f, int h, char* smem) {
  ushort (*Ks)[2048] = (ushort(*)[2048])smem;
  ushort (*Vs)[2048] = (ushort(*)[2048])(smem + 12288);
  int tid = threadIdx.x;
  int wid = tid >> 6, lane = tid & 63;
  int lg = lane >> 4, lr = lane & 15;
  int g = 0;
  while (f >= 4 * (g + 1) * (g + 2)) ++g;
  int r_ = f - 4 * g * (g + 1);
  int ns = g + 1;
  int qb = 8 * g + r_ / ns;
  int s = r_ % ns;
  int tiles_total = 2 * qb + 2;
  int per = (tiles_total + ns - 1) / ns;
  int lo = s * per;
  int nloc = min(per, tiles_total - lo);
  int kvh = h >> 2;
  int q0 = qb * 64 + wid * 16;
  int qg = q0 + lr;
  const float SCL = 0.125f * 1.44269504f;
  const float FM = 16.0f;

  const float* qrow = qkv + (size_t)qg * QKV_W + h * HDIM;
  short8 qfr[2];
  #pragma unroll
  for (int c = 0; c < 2; ++c) {
    float4 a = *(const float4*)(qrow + 32*c + 4*lg);
    float4 b = *(const float4*)(qrow + 32*c + 4*lg + 16);
    short8 v;
    v[0]=(short)f2bf(a.x*SCL); v[1]=(short)f2bf(a.y*SCL); v[2]=(short)f2bf(a.z*SCL); v[3]=(short)f2bf(a.w*SCL);
    v[4]=(short)f2bf(b.x*SCL); v[5]=(short)f2bf(b.y*SCL); v[6]=(short)f2bf(b.z*SCL); v[7]=(short)f2bf(b.w*SCL);
    qfr[c] = v;
  }

  const ushort* ksrc = Kpk + (size_t)(kvh * (TT/32) + lo) * 2048 + wid * 512 + lane * 8;
  const ushort* vsrc = Vpk + (size_t)(kvh * (TT/32) + lo) * 2048 + wid * 512 + lane * 8;

  f32x4 o_acc[4] = {};
  float l_st = 0.f;

  auto issue = [&](int tt) {
    int b = tt % 3;
    gload16(ksrc + (size_t)tt * 2048, &Ks[b][wid * 512]);
    gload16(vsrc + (size_t)tt * 2048, &Vs[b][wid * 512]);
  };
  issue(0);
  if (nloc > 1) issue(1);
  for (int tt = 0; tt < nloc; ++tt) {
    if (tt < nloc - 1) asm volatile("s_waitcnt vmcnt(2)" ::: "memory");
    else               asm volatile("s_waitcnt vmcnt(0)" ::: "memory");
    __builtin_amdgcn_s_barrier();
    if (tt + 2 < nloc) issue(tt + 2);
    int t = lo + tt;
    if (t * 32 > q0 + 15) continue;
    int cb = tt % 3;
    f32x4 st[2];
    #pragma unroll
    for (int n = 0; n < 2; ++n) {
      short8 kf0 = *(const short8*)(&Ks[cb][(lg*32 + ((16*n + lr) ^ lg)) * 8]);
      short8 kf1 = *(const short8*)(&Ks[cb][1024 + (lg*32 + ((16*n + lr) ^ lg)) * 8]);
      f32x4 z = {};
      z = __builtin_amdgcn_mfma_f32_16x16x32_bf16(kf0, qfr[0], z, 0, 0, 0);
      st[n] = __builtin_amdgcn_mfma_f32_16x16x32_bf16(kf1, qfr[1], z, 0, 0, 0);
    }
    float p[2][4];
    float psum = 0.f;
    if (t * 32 + 31 <= q0) {
      #pragma unroll
      for (int n = 0; n < 2; ++n)
        #pragma unroll
        for (int i = 0; i < 4; ++i) {
          float pv = exp2f(st[n][i] - FM);
          p[n][i] = pv; psum += pv;
        }
    } else {
      #pragma unroll
      for (int n = 0; n < 2; ++n)
        #pragma unroll
        for (int i = 0; i < 4; ++i) {
          int kvg = t*32 + 16*n + 4*lg + i;
          float pv = (kvg <= qg) ? exp2f(st[n][i] - FM) : 0.f;
          p[n][i] = pv; psum += pv;
        }
    }
    psum += __shfl_xor(psum, 16);
    psum += __shfl_xor(psum, 32);
    l_st += psum;
    union { unsigned u[4]; short8 s8; } pu;
    asm volatile("v_cvt_pk_bf16_f32 %0, %1, %2" : "=v"(pu.u[0]) : "v"(p[0][0]), "v"(p[0][1]));
    asm volatile("v_cvt_pk_bf16_f32 %0, %1, %2" : "=v"(pu.u[1]) : "v"(p[0][2]), "v"(p[0][3]));
    asm volatile("v_cvt_pk_bf16_f32 %0, %1, %2" : "=v"(pu.u[2]) : "v"(p[1][0]), "v"(p[1][1]));
    asm volatile("v_cvt_pk_bf16_f32 %0, %1, %2" : "=v"(pu.u[3]) : "v"(p[1][2]), "v"(p[1][3]));
    short8 pa = pu.s8;
    #pragma unroll
    for (int nd = 0; nd < 4; ++nd) {
      short8 vf = read_b_frag(&Vs[cb][0], lg, 16*nd + lr);
      o_acc[nd] = __builtin_amdgcn_mfma_f32_16x16x32_bf16(pa, vf, o_acc[nd], 0, 0, 0);
    }
  }

  if (ns == 1) {
    #pragma unroll
    for (int i = 0; i < 4; ++i) {
      float lrow = __shfl(l_st, 4*lg + i);
      float inv = 1.0f / lrow;
      int row = q0 + 4*lg + i;
      ushort* op = ob + (size_t)row * (NHEADS*HDIM) + h * HDIM;
      #pragma unroll
      for (int nd = 0; nd < 4; ++nd) {
        int pcol = ((nd >> 1) << 5) + ((lr >> 2) << 3) + ((nd & 1) << 2) + (lr & 3);
        op[pcol] = f2bf(o_acc[nd][i] * inv);
      }
    }
  } else {
    float* pob = po + ((size_t)f * NHEADS + h) * 4096;
    #pragma unroll
    for (int nd = 0; nd < 4; ++nd)
      #pragma unroll
      for (int i = 0; i < 4; ++i)
        pob[(wid * 16 + lg * 4 + i) * 64 + 16 * nd + lr] = o_acc[nd][i];
    if (lg == 0)
      pl[((size_t)f * NHEADS + h) * 64 + wid * 16 + lr] = l_st;
  }
}

// =====================================================================
// FUSED launches
// =====================================================================
// L1: add_rms1 (2048) + packs QKV(768) WO(512) GUSH(384) DSH(192)
__global__ __launch_bounds__(256) void fused_prep_kernel(
    const float* __restrict__ hidden, const float* __restrict__ residual,
    const float* __restrict__ in_ln_w, float* __restrict__ R_A,
    float* __restrict__ HLN, ushort* __restrict__ HLNB,
    const float* __restrict__ Wqkv, ushort* __restrict__ PK_QKV,
    const float* __restrict__ Wo, ushort* __restrict__ PK_WO,
    const float* __restrict__ Wgu_sh, ushort* __restrict__ PK_GUSH,
    const float* __restrict__ Wd_sh, ushort* __restrict__ PK_DSH) {
  __shared__ ushort smem[2048];
  int blk = blockIdx.x, tid = threadIdx.x;
  if (blk < 2048) {
    add_rms_body(hidden, residual, in_ln_w, R_A, HLN, HLNB, blk, tid, (float*)smem);
  } else if (blk < 2816) {
    int q = blk - 2048;
    pack_B_body(Wqkv, PK_QKV, QKV_W, 24, q / 24, q % 24, smem, tid);
  } else if (blk < 3328) {
    int q = blk - 2816;
    pack_B_body(Wo, PK_WO, HH, 16, q / 16, q % 16, smem, tid);
  } else if (blk < 3712) {
    int q = blk - 3328;
    pack_B_body(Wgu_sh, PK_GUSH, 2*ISHARED, 12, q / 12, q % 12, smem, tid);
  } else {
    int q = blk - 3712;
    pack_B_body(Wd_sh, PK_DSH, HH, 16, q / 16, q % 16, smem, tid);
  }
}

// L5: attn (1280) + WGU pack (12288) + WD pack (6144)
__global__ __launch_bounds__(256) void fused_attn_kernel(
    const float* __restrict__ qkv, const ushort* __restrict__ Kpk,
    const ushort* __restrict__ Vpk, ushort* __restrict__ ob,
    float* __restrict__ po, float* __restrict__ pl,
    const float* __restrict__ Wgu, ushort* __restrict__ PK_WGU,
    const float* __restrict__ Wd, ushort* __restrict__ PK_WD) {
  __shared__ char smem[24576];
  int blk = blockIdx.x, tid = threadIdx.x;
  if (blk < 1280) {
    attn_body(qkv, Kpk, Vpk, ob, po, pl, blk % NSPLITS, blk / NSPLITS, smem);
  } else if (blk < 13568) {
    int q = blk - 1280;
    pack_B_body(Wgu, PK_WGU, 2*IMID, 12, q / 12, q % 12, (ushort*)smem, tid);
  } else {
    int q = blk - 13568;
    pack_B_body(Wd, PK_WD, HH, 16, q / 16, q % 16, (ushort*)smem, tid);
  }
}

// L12: GUSH gemm (384) + moe_up (864)
__global__ __launch_bounds__(256) void fused_up_kernel(
    const ushort* __restrict__ hln2b, const ushort* __restrict__ PK_WGU,
    const int* __restrict__ perm, const int* __restrict__ offs,
    const int* __restrict__ counts, const int* __restrict__ sb_e,
    const int* __restrict__ sb_base, const int* __restrict__ nsb,
    ushort* __restrict__ actb,
    const ushort* __restrict__ PK_GUSH, float* __restrict__ gus_out) {
  __shared__ char smem[32768];
  int blk = blockIdx.x;
  if (blk < 384) {
    gemm64_body(hln2b, PK_GUSH, gus_out, TT, 2*ISHARED, HH, blk % 12, blk / 12, smem);
  } else {
    int q = blk - 384;
    moe_up_body(hln2b, PK_WGU, perm, offs, counts, sb_e, sb_base, nsb, actb,
                q % MAXSB, q / MAXSB);
  }
}

// L14: DSH gemm (512) + moe_down (4608)
__global__ __launch_bounds__(256) void fused_down_kernel(
    const ushort* __restrict__ actb, const ushort* __restrict__ PK_WD,
    const int* __restrict__ offs, const int* __restrict__ counts,
    const int* __restrict__ sb_e, const int* __restrict__ sb_base,
    const int* __restrict__ nsb, ushort* __restrict__ partialb,
    const ushort* __restrict__ shsb, const ushort* __restrict__ PK_DSH,
    float* __restrict__ shared_out) {
  __shared__ char smem[32768];
  int blk = blockIdx.x;
  if (blk < 512) {
    gemm64_body(shsb, PK_DSH, shared_out, TT, HH, ISHARED, blk % 16, blk / 16, smem);
  } else {
    int q = blk - 512;
    moe_down_body(actb, PK_WD, offs, counts, sb_e, sb_base, nsb, partialb,
                  q % MAXSB, q / MAXSB, smem);
  }
}

// =====================================================================
// per-(t,head) QK RMSNorm + RoPE, in-place (f32) — unchanged
// =====================================================================
__global__ __launch_bounds__(256) void qk_norm_rope_kernel(
    float* __restrict__ qkv, const float* __restrict__ qw,
    const float* __restrict__ kw, const int* __restrict__ pos) {
  int t = blockIdx.x;
  int hh = blockIdx.y * 4 + (threadIdx.x >> 6);
  int lane = threadIdx.x & 63;
  float* p = qkv + (size_t)t * QKV_W + hh * HDIM;
  float x = p[lane];
  float ss = x * x;
  #pragma unroll
  for (int off = 1; off < 64; off <<= 1) ss += __shfl_xor(ss, off);
  float r = rsqrtf(ss * (1.0f/HDIM) + EPS_);
  float wv = (hh < NHEADS ? qw : kw)[lane];
  float xn = x * r * wv;
  float partner = __shfl_xor(xn, 16);
  float out = xn;
  if (lane < 32) {
    int i = lane & 15;
    float inv = powf(10000.0f, -(float)i / 16.0f);
    float ang = (float)pos[t] * inv;
    float cv = cosf(ang), sv = sinf(ang);
    out = (lane < 16) ? (xn * cv - partner * sv) : (partner * sv + xn * cv);
  }
  p[lane] = out;
}

// =====================================================================
// pack_KV (unchanged)
// =====================================================================
__global__ __launch_bounds__(256) void pack_KV_kernel(
    const float* __restrict__ qkv, ushort* __restrict__ Kpk,
    ushort* __restrict__ Vpk) {
  __shared__ ushort kimg[2048];
  __shared__ ushort vimg[2048];
  int tid = threadIdx.x;
  int kt = blockIdx.x, kvh = blockIdx.y;
  {
    int c = tid >> 7, t2 = tid & 127;
    int g = t2 & 3, r = t2 >> 2;
    const float* kp = qkv + (size_t)(kt*32 + r) * QKV_W + NHEADS*HDIM + kvh*HDIM + 32*c + 4*g;
    float4 h0 = *(const float4*)kp;
    float4 h1 = *(const float4*)(kp + 16);
    short8 v;
    v[0]=(short)f2bf(h0.x); v[1]=(short)f2bf(h0.y); v[2]=(short)f2bf(h0.z); v[3]=(short)f2bf(h0.w);
    v[4]=(short)f2bf(h1.x); v[5]=(short)f2bf(h1.y); v[6]=(short)f2bf(h1.z); v[7]=(short)f2bf(h1.w);
    *(short8*)(kimg + c*1024 + (g*32 + (r^g))*8) = v;
  }
  stage_B_tile(qkv + (size_t)(NHEADS+NKVH)*HDIM + (size_t)kvh*HDIM, QKV_W, kt*32, 0, vimg, tid);
  __syncthreads();
  size_t toff = ((size_t)(kvh * (TT/32) + kt)) * 2048;
  *(short8*)(Kpk + toff + tid * 8) = *(const short8*)(kimg + tid * 8);
  *(short8*)(Vpk + toff + tid * 8) = *(const short8*)(vimg + tid * 8);
}

// =====================================================================
// attn combine (unchanged)
// =====================================================================
__global__ __launch_bounds__(256) void attn_combine_kernel(
    const float* __restrict__ po, const float* __restrict__ pl,
    ushort* __restrict__ ob) {
  int h = blockIdx.x;
  int qb = 8 + blockIdx.y;
  int g = qb >> 3;
  int ns = g + 1;
  int f0 = 4 * g * (g + 1) + (qb - 8 * g) * ns;
  int tid = threadIdx.x;
  int r = tid >> 2, c = tid & 3;
  float acc[16] = {};
  float lsum = 0.f;
  for (int s = 0; s < ns; ++s) {
    size_t base = ((size_t)(f0 + s) * NHEADS + h) * 4096 + r * 64 + c * 16;
    #pragma unroll
    for (int j = 0; j < 4; ++j) {
      float4 v = *(const float4*)(po + base + j * 4);
      acc[j*4+0] += v.x; acc[j*4+1] += v.y; acc[j*4+2] += v.z; acc[j*4+3] += v.w;
    }
    lsum += pl[((size_t)(f0 + s) * NHEADS + h) * 64 + r];
  }
  float inv = 1.0f / lsum;
  int row = qb * 64 + r;
  ushort* op = ob + (size_t)row * (NHEADS*HDIM) + h * HDIM + (c >> 1) * 32 + (c & 1) * 4;
  #pragma unroll
  for (int a = 0; a < 4; ++a) {
    ushort4 u;
    u.x = f2bf(acc[a*4+0] * inv); u.y = f2bf(acc[a*4+1] * inv);
    u.z = f2bf(acc[a*4+2] * inv); u.w = f2bf(acc[a*4+3] * inv);
    *(ushort4*)(op + a * 8) = u;
  }
}

// =====================================================================
// add_rms standalone (for post-attn), router, count+scan, scatter,
// silu, final_combine
// =====================================================================
__global__ __launch_bounds__(256) void add_rms_kernel(
    const float* __restrict__ a, const float* __restrict__ b,
    const float* __restrict__ w, float* __restrict__ sum_out,
    float* __restrict__ ln_out, ushort* __restrict__ lnb) {
  __shared__ float wsum[4];
  add_rms_body(a, b, w, sum_out, ln_out, lnb, blockIdx.x, threadIdx.x, wsum);
}

__global__ __launch_bounds__(256) void router_kernel(
    const float* __restrict__ hln, const float* __restrict__ Wg,
    const float* __restrict__ bias, int* __restrict__ sel_e,
    float* __restrict__ sel_w) {
  __shared__ float hid[4][HH];
  int tid = threadIdx.x, wid = tid >> 6, lane = tid & 63;
  int t = blockIdx.x * 4 + wid;
  const float4* src = (const float4*)(hln + (size_t)t * HH);
  float4* dst = (float4*)hid[wid];
  #pragma unroll
  for (int j = 0; j < 4; ++j) dst[j * 64 + lane] = src[j * 64 + lane];
  int e = lane & 31, half = lane >> 5;
  const float* wp = Wg + (size_t)(half * 512) * NEXP + e;
  const float* hp = hid[wid] + half * 512;
  float p = 0.f;
  #pragma unroll 8
  for (int h = 0; h < 512; ++h) p += hp[h] * wp[(size_t)h * NEXP];
  p += __shfl_xor(p, 32);
  float sc = 1.0f / (1.0f + expf(-p));
  float sfc = sc + bias[e];
  float m1 = sfc, m2 = -1e30f;
  #pragma unroll
  for (int off = 1; off <= 4; off <<= 1) {
    float om1 = __shfl_xor(m1, off), om2 = __shfl_xor(m2, off);
    float hi_ = fmaxf(m1, om1);
    float lo_ = fmaxf(fminf(m1, om1), fmaxf(m2, om2));
    m1 = hi_; m2 = lo_;
  }
  float gs = m1 + m2;
  float gv[4] = {__shfl(gs, 0), __shfl(gs, 8), __shfl(gs, 16), __shfl(gs, 24)};
  int g1 = 0; float b1 = gv[0];
  #pragma unroll
  for (int g = 1; g < 4; ++g) if (gv[g] > b1) { b1 = gv[g]; g1 = g; }
  int g2 = -1; float b2 = -1e30f;
  #pragma unroll
  for (int g = 0; g < 4; ++g) if (g != g1 && gv[g] > b2) { b2 = gv[g]; g2 = g; }
  bool keep = ((e >> 3) == g1) || ((e >> 3) == g2);
  float cand = keep ? sfc : -1e30f;
  int ids[4]; float wv[4]; float wsum = 0.f;
  #pragma unroll
  for (int s = 0; s < 4; ++s) {
    float v = cand; int ix = e;
    #pragma unroll
    for (int off = 1; off < 64; off <<= 1) {
      float ov = __shfl_xor(v, off); int oix = __shfl_xor(ix, off);
      if (ov > v || (ov == v && oix < ix)) { v = ov; ix = oix; }
    }
    ids[s] = ix;
    if (e == ix) cand = -1e30f;
    float w = __shfl(sc, ix);
    wv[s] = w; wsum += w;
  }
  if (lane == 0) {
    #pragma unroll
    for (int s = 0; s < 4; ++s) {
      sel_e[t * 4 + s] = ids[s];
      sel_w[t * 4 + s] = wv[s] / wsum;
    }
  }
}

// merged count + scan (single block): LDS histogram + serial scan/table
__global__ __launch_bounds__(256) void count_scan_kernel(
    const int* __restrict__ sel_e, int* __restrict__ counts,
    int* __restrict__ offs, int* __restrict__ cursor,
    int* __restrict__ sb_e, int* __restrict__ sb_base, int* __restrict__ nsb) {
  __shared__ int cnt[NEXP];
  int tid = threadIdx.x;
  if (tid < NEXP) cnt[tid] = 0;
  __syncthreads();
  for (int i = tid; i < TT * TOPK_; i += 256) atomicAdd(&cnt[sel_e[i]], 1);
  __syncthreads();
  if (tid == 0) {
    int acc = 0, n = 0;
    for (int e = 0; e < NEXP; ++e) {
      int c = cnt[e];
      counts[e] = c;
      offs[e] = acc; cursor[e] = acc;
      for (int b = 0; b < c; b += 32) { sb_e[n] = e; sb_base[n] = b; ++n; }
      acc += c;
    }
    *nsb = n;
  }
}

__global__ void scatter_kernel(const int* __restrict__ sel_e,
                               int* __restrict__ cursor, int* __restrict__ perm,
                               int* __restrict__ ipos) {
  int i = blockIdx.x * 256 + threadIdx.x;
  if (i < TT * TOPK_) {
    int e = sel_e[i];
    int pos = atomicAdd(&cursor[e], 1);
    perm[pos] = i;
    ipos[i] = pos;
  }
}

__global__ __launch_bounds__(256) void silu_shared_kernel(
    const float* __restrict__ gus, ushort* __restrict__ shsb) {
  int i = blockIdx.x * 256 + threadIdx.x;
  if (i < TT * (ISHARED/4)) {
    int t = i / (ISHARED/4), k = i % (ISHARED/4);
    const float* gp = gus + (size_t)t * (2*ISHARED) + k * 4;
    float4 g4 = *(const float4*)gp;
    float4 u4 = *(const float4*)(gp + ISHARED);
    ushort4 r;
    r.x = f2bf(g4.x / (1.f + expf(-g4.x)) * u4.x);
    r.y = f2bf(g4.y / (1.f + expf(-g4.y)) * u4.y);
    r.z = f2bf(g4.z / (1.f + expf(-g4.z)) * u4.z);
    r.w = f2bf(g4.w / (1.f + expf(-g4.w)) * u4.w);
    int pdst = ((k >> 3) << 5) + ((k & 3) << 3) + (((k >> 2) & 1) << 2);
    *(ushort4*)(shsb + (size_t)t * ISHARED + pdst) = r;
  }
}

__global__ __launch_bounds__(256) void final_combine_kernel(
    const ushort* __restrict__ partialb, const float* __restrict__ sel_w,
    const int* __restrict__ ipos, const float* __restrict__ shared_out,
    float* __restrict__ out_hidden) {
  int t = blockIdx.x, tid = threadIdx.x;
  float w0 = sel_w[t*4], w1 = sel_w[t*4+1], w2 = sel_w[t*4+2], w3 = sel_w[t*4+3];
  int p0 = ipos[t*4], p1 = ipos[t*4+1], p2 = ipos[t*4+2], p3 = ipos[t*4+3];
  ushort4 a0 = *(const ushort4*)(partialb + (size_t)p0*HH + tid*4);
  ushort4 a1 = *(const ushort4*)(partialb + (size_t)p1*HH + tid*4);
  ushort4 a2 = *(const ushort4*)(partialb + (size_t)p2*HH + tid*4);
  ushort4 a3 = *(const ushort4*)(partialb + (size_t)p3*HH + tid*4);
  float4 sh = reinterpret_cast<const float4*>(shared_out + (size_t)t*HH)[tid];
  float4 r;
  r.x = (w0*bf2f(a0.x) + w1*bf2f(a1.x) + w2*bf2f(a2.x) + w3*bf2f(a3.x)) + sh.x;
  r.y = (w0*bf2f(a0.y) + w1*bf2f(a1.y) + w2*bf2f(a2.y) + w3*bf2f(a3.y)) + sh.y;
  r.z = (w0*bf2f(a0.z) + w1*bf2f(a1.z) + w2*bf2f(a2.z) + w3*bf2f(a3.z)) + sh.z;
  r.w = (w0*bf2f(a0.w) + w1*bf2f(a1.w) + w2*bf2f(a2.w) + w3*bf2f(a3.w)) + sh.w;
  reinterpret_cast<float4*>(out_hidden + (size_t)t*HH)[tid] = r;
}

// =====================================================================
extern "C" void kernel_launch(void* const* d_in, const int* in_sizes, int n_in,
                              void* d_out, int out_size, void* d_ws, size_t ws_size,
                              hipStream_t stream) {
  const float* hidden   = (const float*)d_in[0];
  const float* residual = (const float*)d_in[1];
  const float* in_ln_w  = (const float*)d_in[2];
  const float* post_ln_w= (const float*)d_in[3];
  const float* q_norm_w = (const float*)d_in[4];
  const float* k_norm_w = (const float*)d_in[5];
  const float* Wqkv     = (const float*)d_in[6];
  const float* Wo       = (const float*)d_in[7];
  const float* Wg       = (const float*)d_in[8];
  const float* gate_bias= (const float*)d_in[9];
  const float* Wgu      = (const float*)d_in[10];
  const float* Wd       = (const float*)d_in[11];
  const float* Wgu_sh   = (const float*)d_in[12];
  const float* Wd_sh    = (const float*)d_in[13];
  const int*   positions= (const int*)d_in[14];
  float* out = (float*)d_out;

  float* f = (float*)d_ws;
  size_t off = 0;
  float* R_A   = f + off; off += (size_t)TT*HH;
  float* HLN   = f + off; off += (size_t)TT*HH;
  float* QKV   = f + off; off += (size_t)TT*QKV_W;        // reused as gus
  float* OATT  = f + off; off += (size_t)TT*HH;           // DSH output (shared_out)
  float* HLN2  = f + off; off += (size_t)TT*HH;
  float* SELW  = f + off; off += (size_t)TT*TOPK_;
  float* PO    = f + off; off += (size_t)NSPLITS*NHEADS*4096;  // attn partial O
  float* PL    = f + off; off += (size_t)NSPLITS*NHEADS*64;    // attn partial l
  ushort* HLNB  = (ushort*)(f + off); off += (size_t)TT*HH/2;
  ushort* HLN2B = (ushort*)(f + off); off += (size_t)TT*HH/2;
  ushort* OATTB = (ushort*)(f + off); off += (size_t)TT*HH/2;
  ushort* SHSB  = (ushort*)(f + off); off += (size_t)TT*ISHARED/2;
  ushort* KPK   = (ushort*)(f + off); off += (size_t)NKVH*(TT/32)*2048/2;
  ushort* VPK   = (ushort*)(f + off); off += (size_t)NKVH*(TT/32)*2048/2;
  ushort* ACTB  = (ushort*)(f + off); off += (size_t)(TT*TOPK_ + 128)*IMID/2;
  ushort* PARTB = (ushort*)(f + off); off += (size_t)TT*TOPK_*HH/2;
  ushort* PK_QKV = (ushort*)(f + off); off += (size_t)HH*QKV_W/2;
  ushort* PK_WO  = (ushort*)(f + off); off += (size_t)HH*HH/2;
  ushort* PK_WGU = (ushort*)(f + off); off += (size_t)NEXP*HH*(2*IMID)/2;
  ushort* PK_WD  = (ushort*)(f + off); off += (size_t)NEXP*IMID*HH/2;
  ushort* PK_GUSH= (ushort*)(f + off); off += (size_t)HH*(2*ISHARED)/2;
  ushort* PK_DSH = (ushort*)(f + off); off += (size_t)ISHARED*HH/2;
  int* ibase   = (int*)(f + off);
  int* SELE    = ibase;
  int* PERM    = ibase + TT*TOPK_;
  int* IPOS    = ibase + 2*TT*TOPK_;
  int* COUNTS  = ibase + 3*TT*TOPK_;
  int* OFFS    = COUNTS + NEXP;
  int* CURSOR  = OFFS + NEXP;
  int* SB_E    = CURSOR + NEXP;
  int* SB_BASE = SB_E + MAXSB;
  int* NSB     = SB_BASE + MAXSB;

  // L1: add_rms1 + small packs (QKV/WO/GUSH/DSH)
  fused_prep_kernel<<<3904, 256, 0, stream>>>(
      hidden, residual, in_ln_w, R_A, HLN, HLNB,
      Wqkv, PK_QKV, Wo, PK_WO, Wgu_sh, PK_GUSH, Wd_sh, PK_DSH);
  // L2: qkv gemm
  gemm64_bb<<<dim3(QKV_W/64, TT/64), 256, 0, stream>>>(HLNB, PK_QKV, QKV, TT, QKV_W, HH);
  // L3: rope
  qk_norm_rope_kernel<<<dim3(TT, 5), 256, 0, stream>>>(QKV, q_norm_w, k_norm_w, positions);
  // L4: pack KV
  pack_KV_kernel<<<dim3(TT/32, NKVH), 256, 0, stream>>>(QKV, KPK, VPK);
  // L5: attn + WGU/WD packs
  fused_attn_kernel<<<19712, 256, 0, stream>>>(QKV, KPK, VPK, OATTB, PO, PL,
                                               Wgu, PK_WGU, Wd, PK_WD);
  // L6: combine
  attn_combine_kernel<<<dim3(NHEADS, 24), 256, 0, stream>>>(PO, PL, OATTB);
  // L7: Wo gemm
  gemm64_bb<<<dim3(HH/64, TT/64), 256, 0, stream>>>(OATTB, PK_WO, HLN, TT, HH, HH);
  // L8: add_rms2
  add_rms_kernel<<<TT, 256, 0, stream>>>(HLN, R_A, post_ln_w, out + (size_t)TT*HH, HLN2, HLN2B);
  // L9-L11: routing
  router_kernel<<<TT/4, 256, 0, stream>>>(HLN2, Wg, gate_bias, SELE, SELW);
  count_scan_kernel<<<1, 256, 0, stream>>>(SELE, COUNTS, OFFS, CURSOR, SB_E, SB_BASE, NSB);
  scatter_kernel<<<(TT*TOPK_ + 255)/256, 256, 0, stream>>>(SELE, CURSOR, PERM, IPOS);
  // L12: GUSH gemm + moe_up
  fused_up_kernel<<<384 + MAXSB*3, 256, 0, stream>>>(
      HLN2B, PK_WGU, PERM, OFFS, COUNTS, SB_E, SB_BASE, NSB, ACTB, PK_GUSH, QKV);
  // L13: silu
  silu_shared_kernel<<<(TT*(ISHARED/4) + 255)/256, 256, 0, stream>>>(QKV, SHSB);
  // L14: DSH gemm + moe_down
  fused_down_kernel<<<512 + MAXSB*(HH/64), 256, 0, stream>>>(
      ACTB, PK_WD, OFFS, COUNTS, SB_E, SB_BASE, NSB, PARTB, SHSB, PK_DSH, OATT);
  // L15: final combine
  final_combine_kernel<<<TT, 256, 0, stream>>>(PARTB, SELW, IPOS, OATT, out);
}